// Round 9
// baseline (1316.845 us; speedup 1.0000x reference)
//
#include <hip/hip_runtime.h>
#include <hip/hip_bf16.h>

#define B_    64
#define NP_   196
#define NVIS_ 49
#define D_    384
#define DD_   256
#define SENC_ 50
#define SDEC_ 196

typedef __hip_bfloat16 bf16;
typedef __attribute__((ext_vector_type(8))) short short8;
typedef __attribute__((ext_vector_type(4))) float float4v;

__device__ __forceinline__ float bf2f(bf16 x) { return __bfloat162float(x); }
__device__ __forceinline__ bf16 f2bf(float x) { return __float2bfloat16(x); }
__device__ __forceinline__ float rdin(const void* p, long i, int f) {
  return f ? ((const float*)p)[i] : bf2f(((const bf16*)p)[i]);
}
// async global->LDS 16B DMA (gfx950). Size must be literal 16.
__device__ __forceinline__ void gll16(const bf16* g, bf16* l) {
  __builtin_amdgcn_global_load_lds(
      (const __attribute__((address_space(1))) unsigned int*)g,
      (__attribute__((address_space(3))) unsigned int*)l, 16, 0, 0);
}
// counted vmcnt wait (leave lgkmcnt/expcnt unconstrained)
template <int N> __device__ __forceinline__ void waitcnt_vm() {
  if constexpr (N == 0) asm volatile("s_waitcnt vmcnt(0)" ::: "memory");
  else if constexpr (N == 2) asm volatile("s_waitcnt vmcnt(2)" ::: "memory");
  else if constexpr (N == 3) asm volatile("s_waitcnt vmcnt(3)" ::: "memory");
  else if constexpr (N == 4) asm volatile("s_waitcnt vmcnt(4)" ::: "memory");
  else if constexpr (N == 6) asm volatile("s_waitcnt vmcnt(6)" ::: "memory");
}

// ---- dtype probe ----
__global__ void probe_kernel(const void* w, int* flag) {
  int tid = threadIdx.x;
  float mx = 0.f;
  for (int i = tid; i < 512; i += 64)
    mx = fmaxf(mx, fabsf(bf2f(((const bf16*)w)[i])));
#pragma unroll
  for (int off = 32; off; off >>= 1) mx = fmaxf(mx, __shfl_xor(mx, off));
  if (tid == 0) *flag = (mx > 1e3f) ? 1 : 0;  // 1 => inputs are fp32
}

__global__ __launch_bounds__(256) void fill_kernel(bf16* out, float v, int n) {
  int idx = blockIdx.x * 256 + threadIdx.x;
  if (idx < n) out[idx] = f2bf(v);
}

// ---- one-time weight conversion: 11 tensors -> bf16 in workspace ----------
struct WLs { const void* s[11]; long d[11]; int n[11]; };
__global__ __launch_bounds__(256) void wconv_kernel(WLs L, bf16* Wb,
                                                    const int* dflag) {
  int f = *dflag;
  int seg = blockIdx.y;
  long n8 = (long)(L.n[seg] >> 3);
  long i = (long)blockIdx.x * 256 + threadIdx.x;
  if (i >= n8) return;
  bf16* d = Wb + L.d[seg] + i * 8;
  if (f) {
    const float4* s = (const float4*)L.s[seg] + i * 2;
    float4 a = s[0], b = s[1];
    union { uint4 u; bf16 h[8]; } pk;
    pk.h[0] = f2bf(a.x); pk.h[1] = f2bf(a.y); pk.h[2] = f2bf(a.z); pk.h[3] = f2bf(a.w);
    pk.h[4] = f2bf(b.x); pk.h[5] = f2bf(b.y); pk.h[6] = f2bf(b.z); pk.h[7] = f2bf(b.w);
    *(uint4*)d = pk.u;
  } else {
    *(uint4*)d = ((const uint4*)L.s[seg])[i];
  }
}

// ---------------- im2col over VISIBLE patches only -> bf16 ----------------
__global__ __launch_bounds__(256) void im2col_vis_kernel(
    const void* __restrict__ x, const int* __restrict__ unmasked,
    bf16* __restrict__ out, const int* __restrict__ dflag) {
  int f = *dflag;
  int idx = blockIdx.x * 256 + threadIdx.x;
  const int TOT = B_ * NVIS_ * 768;
  if (idx >= TOT) return;
  int k = idx % 768;
  int row = idx / 768;
  int j = row % NVIS_;
  int b = row / NVIS_;
  int n = unmasked[b * NVIS_ + j];
  int ph = n / 14, pw = n % 14;
  int c  = k >> 8;
  int rr = (k >> 4) & 15;
  int cc = k & 15;
  out[idx] = f2bf(rdin(x, (long)(((b * 3 + c) * 224) + ph * 16 + rr) * 224 + pw * 16 + cc, f));
}

// ---- MFMA GEMM: gload_lds staging, dbuf BK=32, counted vmcnt, swizzle -----
// C[M,N] = epi(A[M,K](bf16) @ W[N,K]^T(bf16) + bias)
// MODE 0 plain, 1 exact GELU, 2 += res[f32] (splits must be 1; in-place ok).
// Split-K via grid.z writes DISJOINT f32 partial at C + z*M*N; bias by z==0.
// out_mode: 0 bf16, 1 f32, 2 per dtype flag.
// ROUND-9 single change vs round 8: BK 64->32. Halves LDS dbuf (cfg1 48->24KB,
// cfg2 32->16KB) -> 6-8 blocks/CU (was 3-5) for latency hiding. Counted-vmcnt
// kept (matters more: COMPUTE is shorter vs DMA latency).
// Swizzle (4-chunk domain, key (row>>1)&3): LDS[r][c] = G[r][c ^ ((r>>1)&3)];
// DMA dest stays exactly base + tid*16B (linear, rule-21-safe); read chunk =
// quad ^ ((l16>>1)&3) -> 2-way banks (free, m136).
// Requires M%BM==0, N%BN==0, KS%32==0. NOTE: no 128x128 (m132/round 6).
#define UNR _Pragma("unroll")
template <int MODE, int TMW, int TNW>
__global__ __launch_bounds__(256) void gemm_kernel(
    const bf16* __restrict__ A, const bf16* __restrict__ W,
    const void* __restrict__ bias, long bOff, const float* __restrict__ res,
    void* __restrict__ C, int M, int N, int K, int KS, int out_mode,
    const int* __restrict__ dflag) {
  constexpr int BM = 2 * TMW, BN = 2 * TNW;
  constexpr int AM = TMW / 16, AN = TNW / 16;
  constexpr int ACH = BM / 64, BCH = BN / 64;  // 64-row staging rounds (BK=32)
  constexpr int VW = ACH + BCH;                // DMAs per STAGE per thread
  int f = *dflag;
  __shared__ bf16 Asl[2][BM * 32];
  __shared__ bf16 Bsl[2][BN * 32];
  int tid = threadIdx.x;

  // XCD-chunked bijective remap (m204)
  int gx = gridDim.x;
  int nwg = gx * gridDim.y;
  int orig = blockIdx.y * gx + blockIdx.x;
  int q = nwg >> 3, rr_ = nwg & 7, xcd = orig & 7, off = orig >> 3;
  int wgid = (xcd < rr_ ? xcd * (q + 1) : rr_ * (q + 1) + (xcd - rr_) * q) + off;
  int bx = wgid % gx, by = wgid / gx, bz = blockIdx.z;

  int w = tid >> 6, lane = tid & 63;
  int quad = lane >> 4, l16 = lane & 15;
  int rsw = (l16 >> 1) & 3;  // read-side swizzle key
  int wm = (w & 1) * TMW, wn = (w >> 1) * TNW;
  int srow = tid >> 2;                       // 64 rows per staging round
  int dcol = (tid & 3) * 8;                  // linear dest chunk
  int scol = ((tid & 3) ^ ((srow >> 1) & 3)) * 8;  // XOR-permuted source chunk
  const bf16* Ab = A + (long)by * BM * K;
  const bf16* Wp = W + (long)bx * BN * K;
  int k0lo = bz * KS;

  float4v acc[AM][AN];
#pragma unroll
  for (int i = 0; i < AM; i++)
#pragma unroll
    for (int j = 0; j < AN; j++) acc[i][j] = (float4v){0.f, 0.f, 0.f, 0.f};

#define STAGE(buf, k0) \
  UNR for (int i_ = 0; i_ < ACH; i_++) { \
    int r_ = i_ * 64 + srow; \
    gll16(Ab + (long)r_ * K + (k0) + scol, &Asl[buf][r_ * 32 + dcol]); } \
  UNR for (int i_ = 0; i_ < BCH; i_++) { \
    int r_ = i_ * 64 + srow; \
    gll16(Wp + (long)r_ * K + (k0) + scol, &Bsl[buf][r_ * 32 + dcol]); }

#define COMPUTE(cur) { \
    short8 af[AM], bfr[AN]; \
    UNR for (int mi = 0; mi < AM; mi++) \
      af[mi] = *(const short8*)&Asl[cur][(wm + mi * 16 + l16) * 32 + (quad ^ rsw) * 8]; \
    UNR for (int ni = 0; ni < AN; ni++) \
      bfr[ni] = *(const short8*)&Bsl[cur][(wn + ni * 16 + l16) * 32 + (quad ^ rsw) * 8]; \
    UNR for (int mi = 0; mi < AM; mi++) \
      UNR for (int ni = 0; ni < AN; ni++) \
        acc[mi][ni] = __builtin_amdgcn_mfma_f32_16x16x32_bf16( \
            af[mi], bfr[ni], acc[mi][ni], 0, 0, 0); }

  STAGE(0, k0lo);
  asm volatile("s_waitcnt vmcnt(0)" ::: "memory");
  __builtin_amdgcn_s_barrier();
  int nst = KS >> 5;
  for (int s = 0; s < nst; s++) {
    int cur = s & 1;
    if (s + 1 < nst) {
      STAGE(cur ^ 1, k0lo + (s + 1) * 32);  // stays in flight across barrier
      waitcnt_vm<VW>();                     // only prev stage must be done
    } else {
      asm volatile("s_waitcnt vmcnt(0)" ::: "memory");
    }
    __builtin_amdgcn_s_barrier();  // all waves: cur fully staged
    COMPUTE(cur);
    if (s + 1 < nst) __builtin_amdgcn_s_barrier();  // cur reads done before s+1 STAGE overwrites
  }
#undef STAGE
#undef COMPUTE

  int om = (out_mode == 2) ? (f ? 1 : 0) : out_mode;  // 1=f32, 0=bf16
  float* Cf = (float*)C + (long)bz * M * N;
  bf16*  Cb = (bf16*)C;  // splits never write bf16
#pragma unroll
  for (int mi = 0; mi < AM; mi++) {
#pragma unroll
    for (int ni = 0; ni < AN; ni++) {
      int cn = bx * BN + wn + ni * 16 + l16;
      float bval = (bz == 0) ? rdin(bias, bOff + cn, f) : 0.f;
#pragma unroll
      for (int r = 0; r < 4; r++) {
        int cm = by * BM + wm + mi * 16 + quad * 4 + r;
        float v = acc[mi][ni][r] + bval;
        if constexpr (MODE == 1) v = 0.5f * v * (1.0f + erff(v * 0.70710678f));
        if constexpr (MODE == 2) v += res[(long)cm * N + cn];
        if (om) Cf[(long)cm * N + cn] = v;
        else    Cb[(long)cm * N + cn] = f2bf(v);
      }
    }
  }
}

// ---- LayerNorm fused with residual update: one wave per row --------------
template <int N>
__global__ __launch_bounds__(256) void ln_kernel(
    float* __restrict__ X, const float* __restrict__ G0,
    const float* __restrict__ G1, const float* __restrict__ G2,
    const void* __restrict__ w, long wOff, const void* __restrict__ bv,
    long bOff, bf16* __restrict__ Y, int M, const int* __restrict__ dflag) {
  int f = *dflag;
  int row = blockIdx.x * 4 + (threadIdx.x >> 6);
  int lane = threadIdx.x & 63;
  if (row >= M) return;
  float* xr = X + (long)row * N;
  const float* g0 = G0 ? G0 + (long)row * N : nullptr;
  const float* g1 = G1 ? G1 + (long)row * N : nullptr;
  const float* g2 = G2 ? G2 + (long)row * N : nullptr;
  constexpr int CNT = N / 64;
  float v[CNT];
  float sum = 0.f;
#pragma unroll
  for (int i = 0; i < CNT; i++) {
    int c = lane + 64 * i;
    float t = xr[c];
    if (g0) t += g0[c];
    if (g1) t += g1[c];
    if (g2) t += g2[c];
    if (g0) xr[c] = t;
    v[i] = t;
    sum += t;
  }
#pragma unroll
  for (int off = 32; off; off >>= 1) sum += __shfl_xor(sum, off);
  float mean = sum * (1.0f / N);
  float vs = 0.f;
#pragma unroll
  for (int i = 0; i < CNT; i++) { float d = v[i] - mean; vs += d * d; }
#pragma unroll
  for (int off = 32; off; off >>= 1) vs += __shfl_xor(vs, off);
  float rstd = rsqrtf(vs * (1.0f / N) + 1e-5f);
  bf16* yr = Y + (long)row * N;
#pragma unroll
  for (int i = 0; i < CNT; i++) {
    int cidx = lane + 64 * i;
    yr[cidx] = f2bf((v[i] - mean) * rstd * rdin(w, wOff + cidx, f) + rdin(bv, bOff + cidx, f));
  }
}

// ---- decoder attention, MFMA flash: S=196, DH=32, H=8 --------------------
__global__ __launch_bounds__(256) void attn_dec_kernel(
    const bf16* __restrict__ qkv, bf16* __restrict__ out) {
  const int S = SDEC_, DH = 32, Dm = 256, tri = 768;
  const int KLD = 40, VLD = 232, PLD = 232;
  int b = blockIdx.x >> 3, h = blockIdx.x & 7;
  __shared__ bf16 Ksh[208 * KLD];
  __shared__ bf16 Vt[32 * VLD];
  __shared__ bf16 Psh[4][16 * PLD];
  int tid = threadIdx.x;
  const bf16* base = qkv + (long)b * S * tri;
  for (int idx = tid; idx < S * 4; idx += 256) {
    int s = idx >> 2, part = (idx & 3) * 8;
    uint4 v = *(const uint4*)(base + (long)s * tri + Dm + h * DH + part);
    *(uint4*)(&Ksh[s * KLD + part]) = v;
  }
  if (tid < 12 * 4) {
    int s = 196 + (tid >> 2), part = (tid & 3) * 8;
    uint4 z = {0, 0, 0, 0};
    *(uint4*)(&Ksh[s * KLD + part]) = z;
  }
  for (int idx = tid; idx < S * DH; idx += 256) {
    int s = idx >> 5, d = idx & 31;
    Vt[d * VLD + s] = base[(long)s * tri + 2 * Dm + h * DH + d];
  }
  for (int idx = tid; idx < 32 * 36; idx += 256) {
    int d = idx / 36, c = 196 + idx % 36;
    Vt[d * VLD + c] = f2bf(0.f);
  }
  __syncthreads();
  int w = tid >> 6, lane = tid & 63, l16 = lane & 15, quad = lane >> 4;
  bf16* Pw = &Psh[w][0];
  const float scale = 0.17677669529663687f;
  for (int qt = w; qt < 13; qt += 4) {
    int q0 = qt * 16;
    int qr = min(q0 + l16, S - 1);
    short8 qf = *(const short8*)(base + (long)qr * tri + h * DH + quad * 8);
    float4v sc[13];
#pragma unroll
    for (int t = 0; t < 13; t++) {
      short8 kf = *(const short8*)&Ksh[(t * 16 + l16) * KLD + quad * 8];
      sc[t] = __builtin_amdgcn_mfma_f32_16x16x32_bf16(
          qf, kf, (float4v){0.f, 0.f, 0.f, 0.f}, 0, 0, 0);
    }
    float mx[4] = {-1e30f, -1e30f, -1e30f, -1e30f};
#pragma unroll
    for (int t = 0; t < 13; t++) {
      bool valid = (t * 16 + l16) < S;
#pragma unroll
      for (int r = 0; r < 4; r++) {
        float v = valid ? sc[t][r] * scale : -1e30f;
        sc[t][r] = v;
        mx[r] = fmaxf(mx[r], v);
      }
    }
#pragma unroll
    for (int off = 1; off < 16; off <<= 1)
#pragma unroll
      for (int r = 0; r < 4; r++) mx[r] = fmaxf(mx[r], __shfl_xor(mx[r], off));
    float sm[4] = {0.f, 0.f, 0.f, 0.f};
#pragma unroll
    for (int t = 0; t < 13; t++)
#pragma unroll
      for (int r = 0; r < 4; r++) {
        float p = __expf(sc[t][r] - mx[r]);
        sc[t][r] = p;
        sm[r] += p;
      }
#pragma unroll
    for (int off = 1; off < 16; off <<= 1)
#pragma unroll
      for (int r = 0; r < 4; r++) sm[r] += __shfl_xor(sm[r], off);
#pragma unroll
    for (int t = 0; t < 14; t++) {
      int col = t * 16 + l16;
#pragma unroll
      for (int r = 0; r < 4; r++) {
        float p = (t < 13) ? sc[t][r] : 0.f;
        Pw[(quad * 4 + r) * PLD + col] = f2bf(p);
      }
    }
    __asm__ volatile("s_waitcnt lgkmcnt(0)" ::: "memory");
    float4v o0 = {0.f, 0.f, 0.f, 0.f}, o1 = {0.f, 0.f, 0.f, 0.f};
#pragma unroll
    for (int kc = 0; kc < 7; kc++) {
      short8 pf = *(const short8*)&Pw[l16 * PLD + kc * 32 + quad * 8];
      short8 v0 = *(const short8*)&Vt[l16 * VLD + kc * 32 + quad * 8];
      short8 v1 = *(const short8*)&Vt[(16 + l16) * VLD + kc * 32 + quad * 8];
      o0 = __builtin_amdgcn_mfma_f32_16x16x32_bf16(pf, v0, o0, 0, 0, 0);
      o1 = __builtin_amdgcn_mfma_f32_16x16x32_bf16(pf, v1, o1, 0, 0, 0);
    }
#pragma unroll
    for (int r = 0; r < 4; r++) {
      int row = q0 + quad * 4 + r;
      if (row < S) {
        float inv = 1.f / sm[r];
        bf16* op = out + ((long)(b * S + row)) * Dm + h * DH;
        op[l16]      = f2bf(o0[r] * inv);
        op[16 + l16] = f2bf(o1[r] * inv);
      }
    }
  }
}

// ---- encoder attention: S=50, DH=64, H=6. 128 thr = 2 waves, j-split ------
__global__ __launch_bounds__(128) void attn_enc_kernel(
    const bf16* __restrict__ qkv, bf16* __restrict__ out) {
  const int S = SENC_, H = 6, DH = 64, Dm = H * DH, tri = 3 * Dm;
  int b = blockIdx.x / H, h = blockIdx.x % H;
  int tid = threadIdx.x;
  __shared__ float Ks[SENC_ * 64];
  __shared__ float Vs[SENC_ * 64];
  __shared__ float P1[SENC_ * 66];
  const bf16* base = qkv + (long)b * S * tri;
  for (int idx = tid; idx < S * 8; idx += 128) {
    int s = idx >> 3, part = (idx & 7) * 8;
    union { uint4 u; bf16 hh[8]; } kk, vv;
    kk.u = *(const uint4*)(base + (long)s * tri + Dm + h * DH + part);
    vv.u = *(const uint4*)(base + (long)s * tri + 2 * Dm + h * DH + part);
#pragma unroll
    for (int j = 0; j < 8; j++) {
      Ks[s * DH + part + j] = bf2f(kk.hh[j]);
      Vs[s * DH + part + j] = bf2f(vv.hh[j]);
    }
  }
  __syncthreads();
  int w = tid >> 6, lane = tid & 63;
  int row = lane;
  float q[DH], o[DH];
  float m = -1e30f, l = 0.f;
  if (lane < S) {
    const float scale = 0.125f;
#pragma unroll
    for (int d = 0; d < DH; d++) {
      q[d] = bf2f(base[(long)row * tri + h * DH + d]) * scale;
      o[d] = 0.f;
    }
    int jlo = w * 25, jhi = jlo + 25;
    for (int j = jlo; j < jhi; j++) {
      float s = 0.f;
#pragma unroll
      for (int d = 0; d < DH; d++) s += q[d] * Ks[j * DH + d];
      float mn = fmaxf(m, s);
      float corr = __expf(m - mn);
      float p = __expf(s - mn);
      l = l * corr + p;
      m = mn;
#pragma unroll
      for (int d = 0; d < DH; d++) o[d] = o[d] * corr + p * Vs[j * DH + d];
    }
    if (w == 1) {
#pragma unroll
      for (int d = 0; d < DH; d++) P1[row * 66 + d] = o[d];
      P1[row * 66 + 64] = m;
      P1[row * 66 + 65] = l;
    }
  }
  __syncthreads();
  if (w == 0 && lane < S) {
    float m1 = P1[row * 66 + 64], l1 = P1[row * 66 + 65];
    float mg = fmaxf(m, m1);
    float e0 = __expf(m - mg), e1 = __expf(m1 - mg);
    float lg = l * e0 + l1 * e1;
    float inv = 1.f / lg;
    bf16* op = out + ((long)(b * S + row) * Dm + h * DH);
#pragma unroll
    for (int d = 0; d < DH; d++)
      op[d] = f2bf((o[d] * e0 + P1[row * 66 + d] * e1) * inv);
  }
}

// ---------------- small elementwise kernels ----------------
__global__ __launch_bounds__(256) void build_xe_kernel(
    const float* __restrict__ G0, const float* __restrict__ G1,
    const float* __restrict__ G2, const void* __restrict__ cls,
    const void* __restrict__ pos, const int* __restrict__ unmasked,
    float* __restrict__ xe, const int* __restrict__ dflag) {
  int f = *dflag;
  int idx = blockIdx.x * 256 + threadIdx.x;
  const int TOT = B_ * SENC_ * D_;
  if (idx >= TOT) return;
  int d = idx % D_;
  int s = (idx / D_) % SENC_;
  int b = idx / (D_ * SENC_);
  float v;
  if (s == 0) {
    v = rdin(cls, d, f) + rdin(pos, d, f);
  } else {
    int j = s - 1;
    int n = unmasked[b * NVIS_ + j];
    long r = (long)(b * NVIS_ + j) * D_ + d;
    v = G0[r] + G1[r] + G2[r] + rdin(pos, (long)(1 + n) * D_ + d, f);
  }
  xe[idx] = v;
}

__global__ __launch_bounds__(256) void dec_init_kernel(
    const void* __restrict__ mask_token, const void* __restrict__ dpos,
    float* __restrict__ full, const int* __restrict__ dflag) {
  int f = *dflag;
  int idx = blockIdx.x * 256 + threadIdx.x;
  const int TOT = B_ * NP_ * DD_;
  if (idx >= TOT) return;
  int d = idx % DD_;
  int n = (idx / DD_) % NP_;
  full[idx] = rdin(mask_token, d, f) + rdin(dpos, (long)(1 + n) * DD_ + d, f);
}

__global__ __launch_bounds__(256) void dec_scatter_kernel(
    const float* __restrict__ Gx0, const float* __restrict__ Gx1,
    const int* __restrict__ unmasked, const void* __restrict__ dpos,
    float* __restrict__ full, const int* __restrict__ dflag) {
  int f = *dflag;
  int idx = blockIdx.x * 256 + threadIdx.x;
  const int TOT = B_ * NVIS_ * DD_;
  if (idx >= TOT) return;
  int d = idx % DD_;
  int j = (idx / DD_) % NVIS_;
  int b = idx / (DD_ * NVIS_);
  int n = unmasked[b * NVIS_ + j];
  long r = (long)(b * SENC_ + 1 + j) * DD_ + d;
  full[((long)(b * NP_ + n)) * DD_ + d] =
      Gx0[r] + Gx1[r] + rdin(dpos, (long)(1 + n) * DD_ + d, f);
}

// ---------------- host ----------------
extern "C" void kernel_launch(void* const* d_in, const int* in_sizes, int n_in,
                              void* d_out, int out_size, void* d_ws, size_t ws_size,
                              hipStream_t stream) {
  (void)in_sizes; (void)n_in;
  const int* unmasked = (const int*)d_in[1];
  const int M_ENC = B_ * SENC_;  // 3200
  const int M_DEC = B_ * NP_;    // 12544

  const size_t NEEDED = 87588880;
  if (ws_size < NEEDED) {
    fill_kernel<<<(out_size + 255) / 256, 256, 0, stream>>>(
        (bf16*)d_out, (float)(ws_size >> 20), out_size);
    return;
  }
  char* wsb = (char*)d_ws;
  bf16*  big    = (bf16*)wsb;
  float* full   = (float*)(wsb + 25690112);
  bf16*  im2col = (bf16*)(wsb + 25690112);
  bf16*  t0     = (bf16*)(wsb + 38535168);
  float* xe     = (float*)(wsb + 44957696);
  int*   dflag  = (int*)(wsb + 58884096);
  bf16*  Wb     = (bf16*)(wsb + 58884112);  // 16B-aligned bf16 weights
  float* Gp0 = (float*)(wsb + 0);
  float* Gp1 = (float*)(wsb + 4915200);
  float* Gp2 = (float*)(wsb + 9830400);
  float* Gf0 = (float*)(wsb + 9830400);
  float* Gf1 = (float*)(wsb + 14745600);
  float* Gf2 = (float*)(wsb + 19660800);
  float* Gx0 = (float*)(wsb + 0);
  float* Gx1 = (float*)(wsb + 3276800);

  // bf16 weight offsets (elements)
  const long o_conv = 0,        o_eqkv = 294912,  o_eout = 2949120;
  const long o_efc1 = 3833856,  o_efc2 = 7372800, o_demb = 10911744;
  const long o_dqkv = 11010048, o_dout = 11796480, o_dfc1 = 12058624;
  const long o_dfc2 = 13107200, o_pred = 14155776;

  probe_kernel<<<1, 64, 0, stream>>>(d_in[3], dflag);
  {
    WLs L;
    L.s[0] = d_in[3];  L.d[0] = o_conv; L.n[0] = 294912;
    L.s[1] = d_in[9];  L.d[1] = o_eqkv; L.n[1] = 2654208;
    L.s[2] = d_in[11]; L.d[2] = o_eout; L.n[2] = 884736;
    L.s[3] = d_in[15]; L.d[3] = o_efc1; L.n[3] = 3538944;
    L.s[4] = d_in[17]; L.d[4] = o_efc2; L.n[4] = 3538944;
    L.s[5] = d_in[21]; L.d[5] = o_demb; L.n[5] = 98304;
    L.s[6] = d_in[27]; L.d[6] = o_dqkv; L.n[6] = 786432;
    L.s[7] = d_in[29]; L.d[7] = o_dout; L.n[7] = 262144;
    L.s[8] = d_in[33]; L.d[8] = o_dfc1; L.n[8] = 1048576;
    L.s[9] = d_in[35]; L.d[9] = o_dfc2; L.n[9] = 1048576;
    L.s[10] = d_in[39]; L.d[10] = o_pred; L.n[10] = 196608;
    dim3 g((3538944 / 8 + 255) / 256, 11);
    wconv_kernel<<<g, 256, 0, stream>>>(L, Wb, dflag);
  }

  // cfg: 1 -> 128x64 tile (24KB LDS), 2 -> 64x64 (16KB LDS). No 128x128.
  auto gemm = [&](int mode, int cfg, const bf16* A, const bf16* Wp,
                  const void* bias, long bOff, const float* res, void* C,
                  int M, int N, int K, int splits, int out_mode) {
    int BM = (cfg == 2) ? 64 : 128;
    dim3 g(N / 64, M / BM, splits);
    int KS = K / splits;
#define GL(MO, TM, TN) gemm_kernel<MO, TM, TN><<<g, 256, 0, stream>>>( \
        A, Wp, bias, bOff, res, C, M, N, K, KS, out_mode, dflag)
    if (mode == 0) {
      if (cfg == 1) GL(0, 64, 32); else GL(0, 32, 32);
    } else if (mode == 1) {
      if (cfg == 1) GL(1, 64, 32); else GL(1, 32, 32);
    } else {
      if (cfg == 1) GL(2, 64, 32); else GL(2, 32, 32);
    }
#undef GL
  };

  // ---- patchify (visible patches only), split-K x3 -> disjoint partials ----
  {
    int tot = B_ * NVIS_ * 768;
    im2col_vis_kernel<<<(tot + 255) / 256, 256, 0, stream>>>(d_in[0], unmasked, im2col, dflag);
    gemm(0, 2, im2col, Wb + o_conv, d_in[4], 0, nullptr, Gp0, 3200, D_, 768, 3, 1);
    int tot2 = B_ * SENC_ * D_;
    build_xe_kernel<<<(tot2 + 255) / 256, 256, 0, stream>>>(
        Gp0, Gp1, Gp2, d_in[5], d_in[6], unmasked, xe, dflag);
  }

  // ---- encoder: 6 blocks, S=50, D=384, H=6, dh=64 ----
  const float *eg0 = nullptr, *eg1 = nullptr, *eg2 = nullptr;
  for (int i = 0; i < 6; i++) {
    ln_kernel<D_><<<M_ENC / 4, 256, 0, stream>>>(
        xe, eg0, eg1, eg2, d_in[7], (long)i * D_, d_in[8], (long)i * D_, t0, M_ENC, dflag);
    gemm(0, 1, t0, Wb + o_eqkv + (long)i * 3 * D_ * D_, d_in[10], (long)i * 3 * D_, nullptr, big, M_ENC, 3 * D_, D_, 1, 0);
    attn_enc_kernel<<<B_ * 6, 128, 0, stream>>>(big, t0);
    gemm(0, 2, t0, Wb + o_eout + (long)i * D_ * D_, d_in[12], (long)i * D_, nullptr, Gp0, M_ENC, D_, D_, 2, 1);
    ln_kernel<D_><<<M_ENC / 4, 256, 0, stream>>>(
        xe, Gp0, Gp1, nullptr, d_in[13], (long)i * D_, d_in[14], (long)i * D_, t0, M_ENC, dflag);
    gemm(1, 1, t0, Wb + o_efc1 + (long)i * 4 * D_ * D_, d_in[16], (long)i * 4 * D_, nullptr, big, M_ENC, 4 * D_, D_, 1, 0);
    gemm(0, 2, big, Wb + o_efc2 + (long)i * D_ * 4 * D_, d_in[18], (long)i * D_, nullptr, Gf0, M_ENC, D_, 4 * D_, 3, 1);
    eg0 = Gf0; eg1 = Gf1; eg2 = Gf2;
  }
  ln_kernel<D_><<<M_ENC / 4, 256, 0, stream>>>(
      xe, Gf0, Gf1, Gf2, d_in[19], 0, d_in[20], 0, t0, M_ENC, dflag);
  gemm(0, 2, t0, Wb + o_demb, d_in[22], 0, nullptr, Gx0, M_ENC, DD_, D_, 2, 1);

  // ---- assemble decoder input ----
  {
    int tot = B_ * NP_ * DD_;
    dec_init_kernel<<<(tot + 255) / 256, 256, 0, stream>>>(d_in[23], d_in[24], full, dflag);
    int tot2 = B_ * NVIS_ * DD_;
    dec_scatter_kernel<<<(tot2 + 255) / 256, 256, 0, stream>>>(
        Gx0, Gx1, unmasked, d_in[24], full, dflag);
  }

  // ---- decoder: 4 blocks, S=196, D=256, H=8, dh=32 ----
  // residual fused into GEMM epilogue (MODE 2, splits=1): full updated in place
  for (int i = 0; i < 4; i++) {
    ln_kernel<DD_><<<M_DEC / 4, 256, 0, stream>>>(
        full, nullptr, nullptr, nullptr, d_in[25], (long)i * DD_, d_in[26], (long)i * DD_, t0, M_DEC, dflag);
    gemm(0, 1, t0, Wb + o_dqkv + (long)i * 3 * DD_ * DD_, d_in[28], (long)i * 3 * DD_, nullptr, big, M_DEC, 3 * DD_, DD_, 1, 0);
    attn_dec_kernel<<<B_ * 8, 256, 0, stream>>>(big, t0);
    gemm(2, 2, t0, Wb + o_dout + (long)i * DD_ * DD_, d_in[30], (long)i * DD_, full, full, M_DEC, DD_, DD_, 1, 1);
    ln_kernel<DD_><<<M_DEC / 4, 256, 0, stream>>>(
        full, nullptr, nullptr, nullptr, d_in[31], (long)i * DD_, d_in[32], (long)i * DD_, t0, M_DEC, dflag);
    gemm(1, 1, t0, Wb + o_dfc1 + (long)i * 4 * DD_ * DD_, d_in[34], (long)i * 4 * DD_, nullptr, big, M_DEC, 4 * DD_, DD_, 1, 0);
    gemm(2, 2, big, Wb + o_dfc2 + (long)i * DD_ * 4 * DD_, d_in[36], (long)i * DD_, full, full, M_DEC, DD_, 4 * DD_, 1, 1);
  }
  ln_kernel<DD_><<<M_DEC / 4, 256, 0, stream>>>(
      full, nullptr, nullptr, nullptr, d_in[37], 0, d_in[38], 0, t0, M_DEC, dflag);

  // ---- predictor head: output dtype follows input dtype ----
  gemm(0, 1, t0, Wb + o_pred, d_in[40], 0, nullptr, d_out, M_DEC, 768, DD_, 1, 2);
}

// Round 10
// 1236.816 us; speedup vs baseline: 1.0647x; 1.0647x over previous
//
#include <hip/hip_runtime.h>
#include <hip/hip_bf16.h>

#define B_    64
#define NP_   196
#define NVIS_ 49
#define D_    384
#define DD_   256
#define SENC_ 50
#define SDEC_ 196

typedef __hip_bfloat16 bf16;
typedef __attribute__((ext_vector_type(8))) short short8;
typedef __attribute__((ext_vector_type(4))) float float4v;

__device__ __forceinline__ float bf2f(bf16 x) { return __bfloat162float(x); }
__device__ __forceinline__ bf16 f2bf(float x) { return __float2bfloat16(x); }
__device__ __forceinline__ float rdin(const void* p, long i, int f) {
  return f ? ((const float*)p)[i] : bf2f(((const bf16*)p)[i]);
}
// async global->LDS 16B DMA (gfx950). Size must be literal 16.
__device__ __forceinline__ void gll16(const bf16* g, bf16* l) {
  __builtin_amdgcn_global_load_lds(
      (const __attribute__((address_space(1))) unsigned int*)g,
      (__attribute__((address_space(3))) unsigned int*)l, 16, 0, 0);
}
// counted vmcnt wait (leave lgkmcnt/expcnt unconstrained)
template <int N> __device__ __forceinline__ void waitcnt_vm() {
  if constexpr (N == 0) asm volatile("s_waitcnt vmcnt(0)" ::: "memory");
  else if constexpr (N == 4) asm volatile("s_waitcnt vmcnt(4)" ::: "memory");
  else if constexpr (N == 6) asm volatile("s_waitcnt vmcnt(6)" ::: "memory");
  else if constexpr (N == 8) asm volatile("s_waitcnt vmcnt(8)" ::: "memory");
}

// ---- dtype probe ----
__global__ void probe_kernel(const void* w, int* flag) {
  int tid = threadIdx.x;
  float mx = 0.f;
  for (int i = tid; i < 512; i += 64)
    mx = fmaxf(mx, fabsf(bf2f(((const bf16*)w)[i])));
#pragma unroll
  for (int off = 32; off; off >>= 1) mx = fmaxf(mx, __shfl_xor(mx, off));
  if (tid == 0) *flag = (mx > 1e3f) ? 1 : 0;  // 1 => inputs are fp32
}

__global__ __launch_bounds__(256) void fill_kernel(bf16* out, float v, int n) {
  int idx = blockIdx.x * 256 + threadIdx.x;
  if (idx < n) out[idx] = f2bf(v);
}

// ---- one-time weight conversion: 11 tensors -> bf16 in workspace ----------
struct WLs { const void* s[11]; long d[11]; int n[11]; };
__global__ __launch_bounds__(256) void wconv_kernel(WLs L, bf16* Wb,
                                                    const int* dflag) {
  int f = *dflag;
  int seg = blockIdx.y;
  long n8 = (long)(L.n[seg] >> 3);
  long i = (long)blockIdx.x * 256 + threadIdx.x;
  if (i >= n8) return;
  bf16* d = Wb + L.d[seg] + i * 8;
  if (f) {
    const float4* s = (const float4*)L.s[seg] + i * 2;
    float4 a = s[0], b = s[1];
    union { uint4 u; bf16 h[8]; } pk;
    pk.h[0] = f2bf(a.x); pk.h[1] = f2bf(a.y); pk.h[2] = f2bf(a.z); pk.h[3] = f2bf(a.w);
    pk.h[4] = f2bf(b.x); pk.h[5] = f2bf(b.y); pk.h[6] = f2bf(b.z); pk.h[7] = f2bf(b.w);
    *(uint4*)d = pk.u;
  } else {
    *(uint4*)d = ((const uint4*)L.s[seg])[i];
  }
}

// ---------------- im2col over VISIBLE patches only -> bf16 ----------------
__global__ __launch_bounds__(256) void im2col_vis_kernel(
    const void* __restrict__ x, const int* __restrict__ unmasked,
    bf16* __restrict__ out, const int* __restrict__ dflag) {
  int f = *dflag;
  int idx = blockIdx.x * 256 + threadIdx.x;
  const int TOT = B_ * NVIS_ * 768;
  if (idx >= TOT) return;
  int k = idx % 768;
  int row = idx / 768;
  int j = row % NVIS_;
  int b = row / NVIS_;
  int n = unmasked[b * NVIS_ + j];
  int ph = n / 14, pw = n % 14;
  int c  = k >> 8;
  int rr = (k >> 4) & 15;
  int cc = k & 15;
  out[idx] = f2bf(rdin(x, (long)(((b * 3 + c) * 224) + ph * 16 + rr) * 224 + pw * 16 + cc, f));
}

// ---- MFMA GEMM: gload_lds staging, dbuf BK=64, counted vmcnt, swizzle -----
// ROUND-10: restored verbatim from round 8 (measured best, 1251.7us).
// Tuning history: 128x128/64KB LDS -> -109us (r6, m132); BK=32 -> -65us (r9);
// counted-vmcnt vs __syncthreads on <=48KB tiles -> neutral (r8). This config
// is the local optimum for these shapes; do not re-enter the K-loop.
// C[M,N] = epi(A[M,K](bf16) @ W[N,K]^T(bf16) + bias)
// MODE 0 plain, 1 exact GELU, 2 += res[f32] (splits must be 1; in-place ok).
// Split-K via grid.z writes DISJOINT f32 partial at C + z*M*N; bias by z==0.
// out_mode: 0 bf16, 1 f32, 2 per dtype flag.
// LDS swizzle: linear DMA dest + XOR-permuted global source chunk + same XOR
// on ds_read chunk (rule #21 both-sides). Requires M%BM==0, N%BN==0, KS%64==0.
#define UNR _Pragma("unroll")
template <int MODE, int TMW, int TNW>
__global__ __launch_bounds__(256) void gemm_kernel(
    const bf16* __restrict__ A, const bf16* __restrict__ W,
    const void* __restrict__ bias, long bOff, const float* __restrict__ res,
    void* __restrict__ C, int M, int N, int K, int KS, int out_mode,
    const int* __restrict__ dflag) {
  constexpr int BM = 2 * TMW, BN = 2 * TNW;
  constexpr int AM = TMW / 16, AN = TNW / 16;
  constexpr int ACH = BM / 32, BCH = BN / 32;  // 32-row staging chunks
  constexpr int VW = ACH + BCH;                // DMAs per STAGE per thread
  int f = *dflag;
  __shared__ bf16 Asl[2][BM * 64];
  __shared__ bf16 Bsl[2][BN * 64];
  int tid = threadIdx.x;

  // XCD-chunked bijective remap (m204)
  int gx = gridDim.x;
  int nwg = gx * gridDim.y;
  int orig = blockIdx.y * gx + blockIdx.x;
  int q = nwg >> 3, rr_ = nwg & 7, xcd = orig & 7, off = orig >> 3;
  int wgid = (xcd < rr_ ? xcd * (q + 1) : rr_ * (q + 1) + (xcd - rr_) * q) + off;
  int bx = wgid % gx, by = wgid / gx, bz = blockIdx.z;

  int w = tid >> 6, lane = tid & 63;
  int quad = lane >> 4, l16 = lane & 15;
  int rb = l16 & 7;  // read-side swizzle key
  int wm = (w & 1) * TMW, wn = (w >> 1) * TNW;
  int srow = tid >> 3;
  int dcol = (tid & 7) * 8;
  int scol = (((tid & 7) ^ (srow & 7))) * 8;
  const bf16* Ab = A + (long)by * BM * K;
  const bf16* Wp = W + (long)bx * BN * K;
  int k0lo = bz * KS;

  float4v acc[AM][AN];
#pragma unroll
  for (int i = 0; i < AM; i++)
#pragma unroll
    for (int j = 0; j < AN; j++) acc[i][j] = (float4v){0.f, 0.f, 0.f, 0.f};

#define STAGE(buf, k0) \
  UNR for (int i_ = 0; i_ < ACH; i_++) { \
    int r_ = i_ * 32 + srow; \
    gll16(Ab + (long)r_ * K + (k0) + scol, &Asl[buf][r_ * 64 + dcol]); } \
  UNR for (int i_ = 0; i_ < BCH; i_++) { \
    int r_ = i_ * 32 + srow; \
    gll16(Wp + (long)r_ * K + (k0) + scol, &Bsl[buf][r_ * 64 + dcol]); }

#define COMPUTE(cur) UNR for (int kk = 0; kk < 2; kk++) { \
    short8 af[AM], bfr[AN]; \
    UNR for (int mi = 0; mi < AM; mi++) \
      af[mi] = *(const short8*)&Asl[cur][(wm + mi * 16 + l16) * 64 + ((kk * 4 + quad) ^ rb) * 8]; \
    UNR for (int ni = 0; ni < AN; ni++) \
      bfr[ni] = *(const short8*)&Bsl[cur][(wn + ni * 16 + l16) * 64 + ((kk * 4 + quad) ^ rb) * 8]; \
    UNR for (int mi = 0; mi < AM; mi++) \
      UNR for (int ni = 0; ni < AN; ni++) \
        acc[mi][ni] = __builtin_amdgcn_mfma_f32_16x16x32_bf16( \
            af[mi], bfr[ni], acc[mi][ni], 0, 0, 0); }

  STAGE(0, k0lo);
  asm volatile("s_waitcnt vmcnt(0)" ::: "memory");
  __builtin_amdgcn_s_barrier();
  int nst = KS >> 6;
  for (int s = 0; s < nst; s++) {
    int cur = s & 1;
    if (s + 1 < nst) {
      STAGE(cur ^ 1, k0lo + (s + 1) * 64);  // stays in flight across barrier
      waitcnt_vm<VW>();                     // only prev stage must be done
    } else {
      asm volatile("s_waitcnt vmcnt(0)" ::: "memory");
    }
    __builtin_amdgcn_s_barrier();  // all waves: cur fully staged
    COMPUTE(cur);
    if (s + 1 < nst) __builtin_amdgcn_s_barrier();  // cur reads done before s+1 STAGE overwrites
  }
#undef STAGE
#undef COMPUTE

  int om = (out_mode == 2) ? (f ? 1 : 0) : out_mode;  // 1=f32, 0=bf16
  float* Cf = (float*)C + (long)bz * M * N;
  bf16*  Cb = (bf16*)C;  // splits never write bf16
#pragma unroll
  for (int mi = 0; mi < AM; mi++) {
#pragma unroll
    for (int ni = 0; ni < AN; ni++) {
      int cn = bx * BN + wn + ni * 16 + l16;
      float bval = (bz == 0) ? rdin(bias, bOff + cn, f) : 0.f;
#pragma unroll
      for (int r = 0; r < 4; r++) {
        int cm = by * BM + wm + mi * 16 + quad * 4 + r;
        float v = acc[mi][ni][r] + bval;
        if constexpr (MODE == 1) v = 0.5f * v * (1.0f + erff(v * 0.70710678f));
        if constexpr (MODE == 2) v += res[(long)cm * N + cn];
        if (om) Cf[(long)cm * N + cn] = v;
        else    Cb[(long)cm * N + cn] = f2bf(v);
      }
    }
  }
}

// ---- LayerNorm fused with residual update: one wave per row (generic) ----
template <int N>
__global__ __launch_bounds__(256) void ln_kernel(
    float* __restrict__ X, const float* __restrict__ G0,
    const float* __restrict__ G1, const float* __restrict__ G2,
    const void* __restrict__ w, long wOff, const void* __restrict__ bv,
    long bOff, bf16* __restrict__ Y, int M, const int* __restrict__ dflag) {
  int f = *dflag;
  int row = blockIdx.x * 4 + (threadIdx.x >> 6);
  int lane = threadIdx.x & 63;
  if (row >= M) return;
  float* xr = X + (long)row * N;
  const float* g0 = G0 ? G0 + (long)row * N : nullptr;
  const float* g1 = G1 ? G1 + (long)row * N : nullptr;
  const float* g2 = G2 ? G2 + (long)row * N : nullptr;
  constexpr int CNT = N / 64;
  float v[CNT];
  float sum = 0.f;
#pragma unroll
  for (int i = 0; i < CNT; i++) {
    int c = lane + 64 * i;
    float t = xr[c];
    if (g0) t += g0[c];
    if (g1) t += g1[c];
    if (g2) t += g2[c];
    if (g0) xr[c] = t;
    v[i] = t;
    sum += t;
  }
#pragma unroll
  for (int off = 32; off; off >>= 1) sum += __shfl_xor(sum, off);
  float mean = sum * (1.0f / N);
  float vs = 0.f;
#pragma unroll
  for (int i = 0; i < CNT; i++) { float d = v[i] - mean; vs += d * d; }
#pragma unroll
  for (int off = 32; off; off >>= 1) vs += __shfl_xor(vs, off);
  float rstd = rsqrtf(vs * (1.0f / N) + 1e-5f);
  bf16* yr = Y + (long)row * N;
#pragma unroll
  for (int i = 0; i < CNT; i++) {
    int cidx = lane + 64 * i;
    yr[cidx] = f2bf((v[i] - mean) * rstd * rdin(w, wOff + cidx, f) + rdin(bv, bOff + cidx, f));
  }
}

// ---- LayerNorm N=256, vectorized (G13): lane owns 4 consecutive cols ------
// float4 load + short4 store (4x fewer mem instrs than scalar path). No
// residual inputs: decoder residual is fused into GEMM MODE-2 epilogue.
__global__ __launch_bounds__(256) void ln256_kernel(
    const float* __restrict__ X, const void* __restrict__ w, long wOff,
    const void* __restrict__ bv, long bOff, bf16* __restrict__ Y, int M,
    const int* __restrict__ dflag) {
  int f = *dflag;
  int row = blockIdx.x * 4 + (threadIdx.x >> 6);
  int lane = threadIdx.x & 63;
  if (row >= M) return;
  float4 v = *(const float4*)(X + (long)row * 256 + lane * 4);
  float sum = v.x + v.y + v.z + v.w;
#pragma unroll
  for (int off = 32; off; off >>= 1) sum += __shfl_xor(sum, off);
  float mean = sum * (1.0f / 256.0f);
  float dx = v.x - mean, dy = v.y - mean, dz = v.z - mean, dw = v.w - mean;
  float vs = dx * dx + dy * dy + dz * dz + dw * dw;
#pragma unroll
  for (int off = 32; off; off >>= 1) vs += __shfl_xor(vs, off);
  float rstd = rsqrtf(vs * (1.0f / 256.0f) + 1e-5f);
  float w0, w1, w2, w3, b0, b1, b2, b3;
  if (f) {
    float4 wv = *(const float4*)((const float*)w + wOff + lane * 4);
    float4 bb = *(const float4*)((const float*)bv + bOff + lane * 4);
    w0 = wv.x; w1 = wv.y; w2 = wv.z; w3 = wv.w;
    b0 = bb.x; b1 = bb.y; b2 = bb.z; b3 = bb.w;
  } else {
    const bf16* wp = (const bf16*)w + wOff + lane * 4;
    const bf16* bp = (const bf16*)bv + bOff + lane * 4;
    w0 = bf2f(wp[0]); w1 = bf2f(wp[1]); w2 = bf2f(wp[2]); w3 = bf2f(wp[3]);
    b0 = bf2f(bp[0]); b1 = bf2f(bp[1]); b2 = bf2f(bp[2]); b3 = bf2f(bp[3]);
  }
  union { short4 s4; bf16 h[4]; } o;
  o.h[0] = f2bf(dx * rstd * w0 + b0);
  o.h[1] = f2bf(dy * rstd * w1 + b1);
  o.h[2] = f2bf(dz * rstd * w2 + b2);
  o.h[3] = f2bf(dw * rstd * w3 + b3);
  *(short4*)(Y + (long)row * 256 + lane * 4) = o.s4;
}

// ---- decoder attention, MFMA flash: S=196, DH=32, H=8 --------------------
__global__ __launch_bounds__(256) void attn_dec_kernel(
    const bf16* __restrict__ qkv, bf16* __restrict__ out) {
  const int S = SDEC_, DH = 32, Dm = 256, tri = 768;
  const int KLD = 40, VLD = 232, PLD = 232;
  int b = blockIdx.x >> 3, h = blockIdx.x & 7;
  __shared__ bf16 Ksh[208 * KLD];
  __shared__ bf16 Vt[32 * VLD];
  __shared__ bf16 Psh[4][16 * PLD];
  int tid = threadIdx.x;
  const bf16* base = qkv + (long)b * S * tri;
  for (int idx = tid; idx < S * 4; idx += 256) {
    int s = idx >> 2, part = (idx & 3) * 8;
    uint4 v = *(const uint4*)(base + (long)s * tri + Dm + h * DH + part);
    *(uint4*)(&Ksh[s * KLD + part]) = v;
  }
  if (tid < 12 * 4) {
    int s = 196 + (tid >> 2), part = (tid & 3) * 8;
    uint4 z = {0, 0, 0, 0};
    *(uint4*)(&Ksh[s * KLD + part]) = z;
  }
  for (int idx = tid; idx < S * DH; idx += 256) {
    int s = idx >> 5, d = idx & 31;
    Vt[d * VLD + s] = base[(long)s * tri + 2 * Dm + h * DH + d];
  }
  for (int idx = tid; idx < 32 * 36; idx += 256) {
    int d = idx / 36, c = 196 + idx % 36;
    Vt[d * VLD + c] = f2bf(0.f);
  }
  __syncthreads();
  int w = tid >> 6, lane = tid & 63, l16 = lane & 15, quad = lane >> 4;
  bf16* Pw = &Psh[w][0];
  const float scale = 0.17677669529663687f;
  for (int qt = w; qt < 13; qt += 4) {
    int q0 = qt * 16;
    int qr = min(q0 + l16, S - 1);
    short8 qf = *(const short8*)(base + (long)qr * tri + h * DH + quad * 8);
    float4v sc[13];
#pragma unroll
    for (int t = 0; t < 13; t++) {
      short8 kf = *(const short8*)&Ksh[(t * 16 + l16) * KLD + quad * 8];
      sc[t] = __builtin_amdgcn_mfma_f32_16x16x32_bf16(
          qf, kf, (float4v){0.f, 0.f, 0.f, 0.f}, 0, 0, 0);
    }
    float mx[4] = {-1e30f, -1e30f, -1e30f, -1e30f};
#pragma unroll
    for (int t = 0; t < 13; t++) {
      bool valid = (t * 16 + l16) < S;
#pragma unroll
      for (int r = 0; r < 4; r++) {
        float v = valid ? sc[t][r] * scale : -1e30f;
        sc[t][r] = v;
        mx[r] = fmaxf(mx[r], v);
      }
    }
#pragma unroll
    for (int off = 1; off < 16; off <<= 1)
#pragma unroll
      for (int r = 0; r < 4; r++) mx[r] = fmaxf(mx[r], __shfl_xor(mx[r], off));
    float sm[4] = {0.f, 0.f, 0.f, 0.f};
#pragma unroll
    for (int t = 0; t < 13; t++)
#pragma unroll
      for (int r = 0; r < 4; r++) {
        float p = __expf(sc[t][r] - mx[r]);
        sc[t][r] = p;
        sm[r] += p;
      }
#pragma unroll
    for (int off = 1; off < 16; off <<= 1)
#pragma unroll
      for (int r = 0; r < 4; r++) sm[r] += __shfl_xor(sm[r], off);
#pragma unroll
    for (int t = 0; t < 14; t++) {
      int col = t * 16 + l16;
#pragma unroll
      for (int r = 0; r < 4; r++) {
        float p = (t < 13) ? sc[t][r] : 0.f;
        Pw[(quad * 4 + r) * PLD + col] = f2bf(p);
      }
    }
    __asm__ volatile("s_waitcnt lgkmcnt(0)" ::: "memory");
    float4v o0 = {0.f, 0.f, 0.f, 0.f}, o1 = {0.f, 0.f, 0.f, 0.f};
#pragma unroll
    for (int kc = 0; kc < 7; kc++) {
      short8 pf = *(const short8*)&Pw[l16 * PLD + kc * 32 + quad * 8];
      short8 v0 = *(const short8*)&Vt[l16 * VLD + kc * 32 + quad * 8];
      short8 v1 = *(const short8*)&Vt[(16 + l16) * VLD + kc * 32 + quad * 8];
      o0 = __builtin_amdgcn_mfma_f32_16x16x32_bf16(pf, v0, o0, 0, 0, 0);
      o1 = __builtin_amdgcn_mfma_f32_16x16x32_bf16(pf, v1, o1, 0, 0, 0);
    }
#pragma unroll
    for (int r = 0; r < 4; r++) {
      int row = q0 + quad * 4 + r;
      if (row < S) {
        float inv = 1.f / sm[r];
        bf16* op = out + ((long)(b * S + row)) * Dm + h * DH;
        op[l16]      = f2bf(o0[r] * inv);
        op[16 + l16] = f2bf(o1[r] * inv);
      }
    }
  }
}

// ---- encoder attention: S=50, DH=64, H=6. 128 thr = 2 waves, j-split ------
__global__ __launch_bounds__(128) void attn_enc_kernel(
    const bf16* __restrict__ qkv, bf16* __restrict__ out) {
  const int S = SENC_, H = 6, DH = 64, Dm = H * DH, tri = 3 * Dm;
  int b = blockIdx.x / H, h = blockIdx.x % H;
  int tid = threadIdx.x;
  __shared__ float Ks[SENC_ * 64];
  __shared__ float Vs[SENC_ * 64];
  __shared__ float P1[SENC_ * 66];
  const bf16* base = qkv + (long)b * S * tri;
  for (int idx = tid; idx < S * 8; idx += 128) {
    int s = idx >> 3, part = (idx & 7) * 8;
    union { uint4 u; bf16 hh[8]; } kk, vv;
    kk.u = *(const uint4*)(base + (long)s * tri + Dm + h * DH + part);
    vv.u = *(const uint4*)(base + (long)s * tri + 2 * Dm + h * DH + part);
#pragma unroll
    for (int j = 0; j < 8; j++) {
      Ks[s * DH + part + j] = bf2f(kk.hh[j]);
      Vs[s * DH + part + j] = bf2f(vv.hh[j]);
    }
  }
  __syncthreads();
  int w = tid >> 6, lane = tid & 63;
  int row = lane;
  float q[DH], o[DH];
  float m = -1e30f, l = 0.f;
  if (lane < S) {
    const float scale = 0.125f;
#pragma unroll
    for (int d = 0; d < DH; d++) {
      q[d] = bf2f(base[(long)row * tri + h * DH + d]) * scale;
      o[d] = 0.f;
    }
    int jlo = w * 25, jhi = jlo + 25;
    for (int j = jlo; j < jhi; j++) {
      float s = 0.f;
#pragma unroll
      for (int d = 0; d < DH; d++) s += q[d] * Ks[j * DH + d];
      float mn = fmaxf(m, s);
      float corr = __expf(m - mn);
      float p = __expf(s - mn);
      l = l * corr + p;
      m = mn;
#pragma unroll
      for (int d = 0; d < DH; d++) o[d] = o[d] * corr + p * Vs[j * DH + d];
    }
    if (w == 1) {
#pragma unroll
      for (int d = 0; d < DH; d++) P1[row * 66 + d] = o[d];
      P1[row * 66 + 64] = m;
      P1[row * 66 + 65] = l;
    }
  }
  __syncthreads();
  if (w == 0 && lane < S) {
    float m1 = P1[row * 66 + 64], l1 = P1[row * 66 + 65];
    float mg = fmaxf(m, m1);
    float e0 = __expf(m - mg), e1 = __expf(m1 - mg);
    float lg = l * e0 + l1 * e1;
    float inv = 1.f / lg;
    bf16* op = out + ((long)(b * S + row) * Dm + h * DH);
#pragma unroll
    for (int d = 0; d < DH; d++)
      op[d] = f2bf((o[d] * e0 + P1[row * 66 + d] * e1) * inv);
  }
}

// ---------------- small elementwise kernels ----------------
__global__ __launch_bounds__(256) void build_xe_kernel(
    const float* __restrict__ G0, const float* __restrict__ G1,
    const float* __restrict__ G2, const void* __restrict__ cls,
    const void* __restrict__ pos, const int* __restrict__ unmasked,
    float* __restrict__ xe, const int* __restrict__ dflag) {
  int f = *dflag;
  int idx = blockIdx.x * 256 + threadIdx.x;
  const int TOT = B_ * SENC_ * D_;
  if (idx >= TOT) return;
  int d = idx % D_;
  int s = (idx / D_) % SENC_;
  int b = idx / (D_ * SENC_);
  float v;
  if (s == 0) {
    v = rdin(cls, d, f) + rdin(pos, d, f);
  } else {
    int j = s - 1;
    int n = unmasked[b * NVIS_ + j];
    long r = (long)(b * NVIS_ + j) * D_ + d;
    v = G0[r] + G1[r] + G2[r] + rdin(pos, (long)(1 + n) * D_ + d, f);
  }
  xe[idx] = v;
}

__global__ __launch_bounds__(256) void dec_init_kernel(
    const void* __restrict__ mask_token, const void* __restrict__ dpos,
    float* __restrict__ full, const int* __restrict__ dflag) {
  int f = *dflag;
  int idx = blockIdx.x * 256 + threadIdx.x;
  const int TOT = B_ * NP_ * DD_;
  if (idx >= TOT) return;
  int d = idx % DD_;
  int n = (idx / DD_) % NP_;
  full[idx] = rdin(mask_token, d, f) + rdin(dpos, (long)(1 + n) * DD_ + d, f);
}

__global__ __launch_bounds__(256) void dec_scatter_kernel(
    const float* __restrict__ Gx0, const float* __restrict__ Gx1,
    const int* __restrict__ unmasked, const void* __restrict__ dpos,
    float* __restrict__ full, const int* __restrict__ dflag) {
  int f = *dflag;
  int idx = blockIdx.x * 256 + threadIdx.x;
  const int TOT = B_ * NVIS_ * DD_;
  if (idx >= TOT) return;
  int d = idx % DD_;
  int j = (idx / DD_) % NVIS_;
  int b = idx / (DD_ * NVIS_);
  int n = unmasked[b * NVIS_ + j];
  long r = (long)(b * SENC_ + 1 + j) * DD_ + d;
  full[((long)(b * NP_ + n)) * DD_ + d] =
      Gx0[r] + Gx1[r] + rdin(dpos, (long)(1 + n) * DD_ + d, f);
}

// ---------------- host ----------------
extern "C" void kernel_launch(void* const* d_in, const int* in_sizes, int n_in,
                              void* d_out, int out_size, void* d_ws, size_t ws_size,
                              hipStream_t stream) {
  (void)in_sizes; (void)n_in;
  const int* unmasked = (const int*)d_in[1];
  const int M_ENC = B_ * SENC_;  // 3200
  const int M_DEC = B_ * NP_;    // 12544

  const size_t NEEDED = 87588880;
  if (ws_size < NEEDED) {
    fill_kernel<<<(out_size + 255) / 256, 256, 0, stream>>>(
        (bf16*)d_out, (float)(ws_size >> 20), out_size);
    return;
  }
  char* wsb = (char*)d_ws;
  bf16*  big    = (bf16*)wsb;
  float* full   = (float*)(wsb + 25690112);
  bf16*  im2col = (bf16*)(wsb + 25690112);
  bf16*  t0     = (bf16*)(wsb + 38535168);
  float* xe     = (float*)(wsb + 44957696);
  int*   dflag  = (int*)(wsb + 58884096);
  bf16*  Wb     = (bf16*)(wsb + 58884112);  // 16B-aligned bf16 weights
  float* Gp0 = (float*)(wsb + 0);
  float* Gp1 = (float*)(wsb + 4915200);
  float* Gp2 = (float*)(wsb + 9830400);
  float* Gf0 = (float*)(wsb + 9830400);
  float* Gf1 = (float*)(wsb + 14745600);
  float* Gf2 = (float*)(wsb + 19660800);
  float* Gx0 = (float*)(wsb + 0);
  float* Gx1 = (float*)(wsb + 3276800);

  // bf16 weight offsets (elements)
  const long o_conv = 0,        o_eqkv = 294912,  o_eout = 2949120;
  const long o_efc1 = 3833856,  o_efc2 = 7372800, o_demb = 10911744;
  const long o_dqkv = 11010048, o_dout = 11796480, o_dfc1 = 12058624;
  const long o_dfc2 = 13107200, o_pred = 14155776;

  probe_kernel<<<1, 64, 0, stream>>>(d_in[3], dflag);
  {
    WLs L;
    L.s[0] = d_in[3];  L.d[0] = o_conv; L.n[0] = 294912;
    L.s[1] = d_in[9];  L.d[1] = o_eqkv; L.n[1] = 2654208;
    L.s[2] = d_in[11]; L.d[2] = o_eout; L.n[2] = 884736;
    L.s[3] = d_in[15]; L.d[3] = o_efc1; L.n[3] = 3538944;
    L.s[4] = d_in[17]; L.d[4] = o_efc2; L.n[4] = 3538944;
    L.s[5] = d_in[21]; L.d[5] = o_demb; L.n[5] = 98304;
    L.s[6] = d_in[27]; L.d[6] = o_dqkv; L.n[6] = 786432;
    L.s[7] = d_in[29]; L.d[7] = o_dout; L.n[7] = 262144;
    L.s[8] = d_in[33]; L.d[8] = o_dfc1; L.n[8] = 1048576;
    L.s[9] = d_in[35]; L.d[9] = o_dfc2; L.n[9] = 1048576;
    L.s[10] = d_in[39]; L.d[10] = o_pred; L.n[10] = 196608;
    dim3 g((3538944 / 8 + 255) / 256, 11);
    wconv_kernel<<<g, 256, 0, stream>>>(L, Wb, dflag);
  }

  // cfg: 1 -> 128x64 tile (48KB LDS), 2 -> 64x64 (32KB LDS). No 128x128.
  auto gemm = [&](int mode, int cfg, const bf16* A, const bf16* Wp,
                  const void* bias, long bOff, const float* res, void* C,
                  int M, int N, int K, int splits, int out_mode) {
    int BM = (cfg == 2) ? 64 : 128;
    dim3 g(N / 64, M / BM, splits);
    int KS = K / splits;
#define GL(MO, TM, TN) gemm_kernel<MO, TM, TN><<<g, 256, 0, stream>>>( \
        A, Wp, bias, bOff, res, C, M, N, K, KS, out_mode, dflag)
    if (mode == 0) {
      if (cfg == 1) GL(0, 64, 32); else GL(0, 32, 32);
    } else if (mode == 1) {
      if (cfg == 1) GL(1, 64, 32); else GL(1, 32, 32);
    } else {
      if (cfg == 1) GL(2, 64, 32); else GL(2, 32, 32);
    }
#undef GL
  };

  // ---- patchify (visible patches only), split-K x3 -> disjoint partials ----
  {
    int tot = B_ * NVIS_ * 768;
    im2col_vis_kernel<<<(tot + 255) / 256, 256, 0, stream>>>(d_in[0], unmasked, im2col, dflag);
    gemm(0, 2, im2col, Wb + o_conv, d_in[4], 0, nullptr, Gp0, 3200, D_, 768, 3, 1);
    int tot2 = B_ * SENC_ * D_;
    build_xe_kernel<<<(tot2 + 255) / 256, 256, 0, stream>>>(
        Gp0, Gp1, Gp2, d_in[5], d_in[6], unmasked, xe, dflag);
  }

  // ---- encoder: 6 blocks, S=50, D=384, H=6, dh=64 ----
  const float *eg0 = nullptr, *eg1 = nullptr, *eg2 = nullptr;
  for (int i = 0; i < 6; i++) {
    ln_kernel<D_><<<M_ENC / 4, 256, 0, stream>>>(
        xe, eg0, eg1, eg2, d_in[7], (long)i * D_, d_in[8], (long)i * D_, t0, M_ENC, dflag);
    gemm(0, 1, t0, Wb + o_eqkv + (long)i * 3 * D_ * D_, d_in[10], (long)i * 3 * D_, nullptr, big, M_ENC, 3 * D_, D_, 1, 0);
    attn_enc_kernel<<<B_ * 6, 128, 0, stream>>>(big, t0);
    gemm(0, 2, t0, Wb + o_eout + (long)i * D_ * D_, d_in[12], (long)i * D_, nullptr, Gp0, M_ENC, D_, D_, 2, 1);
    ln_kernel<D_><<<M_ENC / 4, 256, 0, stream>>>(
        xe, Gp0, Gp1, nullptr, d_in[13], (long)i * D_, d_in[14], (long)i * D_, t0, M_ENC, dflag);
    gemm(1, 1, t0, Wb + o_efc1 + (long)i * 4 * D_ * D_, d_in[16], (long)i * 4 * D_, nullptr, big, M_ENC, 4 * D_, D_, 1, 0);
    gemm(0, 2, big, Wb + o_efc2 + (long)i * D_ * 4 * D_, d_in[18], (long)i * D_, nullptr, Gf0, M_ENC, D_, 4 * D_, 3, 1);
    eg0 = Gf0; eg1 = Gf1; eg2 = Gf2;
  }
  ln_kernel<D_><<<M_ENC / 4, 256, 0, stream>>>(
      xe, Gf0, Gf1, Gf2, d_in[19], 0, d_in[20], 0, t0, M_ENC, dflag);
  gemm(0, 2, t0, Wb + o_demb, d_in[22], 0, nullptr, Gx0, M_ENC, DD_, D_, 2, 1);

  // ---- assemble decoder input ----
  {
    int tot = B_ * NP_ * DD_;
    dec_init_kernel<<<(tot + 255) / 256, 256, 0, stream>>>(d_in[23], d_in[24], full, dflag);
    int tot2 = B_ * NVIS_ * DD_;
    dec_scatter_kernel<<<(tot2 + 255) / 256, 256, 0, stream>>>(
        Gx0, Gx1, unmasked, d_in[24], full, dflag);
  }

  // ---- decoder: 4 blocks, S=196, D=256, H=8, dh=32 ----
  // residual fused into GEMM epilogue (MODE 2, splits=1): full updated in place
  for (int i = 0; i < 4; i++) {
    ln256_kernel<<<M_DEC / 4, 256, 0, stream>>>(
        full, d_in[25], (long)i * DD_, d_in[26], (long)i * DD_, t0, M_DEC, dflag);
    gemm(0, 1, t0, Wb + o_dqkv + (long)i * 3 * DD_ * DD_, d_in[28], (long)i * 3 * DD_, nullptr, big, M_DEC, 3 * DD_, DD_, 1, 0);
    attn_dec_kernel<<<B_ * 8, 256, 0, stream>>>(big, t0);
    gemm(2, 2, t0, Wb + o_dout + (long)i * DD_ * DD_, d_in[30], (long)i * DD_, full, full, M_DEC, DD_, DD_, 1, 1);
    ln256_kernel<<<M_DEC / 4, 256, 0, stream>>>(
        full, d_in[31], (long)i * DD_, d_in[32], (long)i * DD_, t0, M_DEC, dflag);
    gemm(1, 1, t0, Wb + o_dfc1 + (long)i * 4 * DD_ * DD_, d_in[34], (long)i * 4 * DD_, nullptr, big, M_DEC, 4 * DD_, DD_, 1, 0);
    gemm(2, 2, big, Wb + o_dfc2 + (long)i * DD_ * 4 * DD_, d_in[36], (long)i * DD_, full, full, M_DEC, DD_, 4 * DD_, 1, 1);
  }
  ln256_kernel<<<M_DEC / 4, 256, 0, stream>>>(
      full, d_in[37], 0, d_in[38], 0, t0, M_DEC, dflag);

  // ---- predictor head: output dtype follows input dtype ----
  gemm(0, 1, t0, Wb + o_pred, d_in[40], 0, nullptr, d_out, M_DEC, 768, DD_, 1, 2);
}

// Round 12
// 1230.891 us; speedup vs baseline: 1.0698x; 1.0048x over previous
//
#include <hip/hip_runtime.h>
#include <hip/hip_bf16.h>

#define B_    64
#define NP_   196
#define NVIS_ 49
#define D_    384
#define DD_   256
#define SENC_ 50
#define SDEC_ 196

typedef __hip_bfloat16 bf16;
typedef __attribute__((ext_vector_type(8))) short short8;
typedef __attribute__((ext_vector_type(4))) float float4v;

__device__ __forceinline__ float bf2f(bf16 x) { return __bfloat162float(x); }
__device__ __forceinline__ bf16 f2bf(float x) { return __float2bfloat16(x); }
__device__ __forceinline__ float rdin(const void* p, long i, int f) {
  return f ? ((const float*)p)[i] : bf2f(((const bf16*)p)[i]);
}
// async global->LDS 16B DMA (gfx950). Size must be literal 16.
__device__ __forceinline__ void gll16(const bf16* g, bf16* l) {
  __builtin_amdgcn_global_load_lds(
      (const __attribute__((address_space(1))) unsigned int*)g,
      (__attribute__((address_space(3))) unsigned int*)l, 16, 0, 0);
}
// counted vmcnt wait (leave lgkmcnt/expcnt unconstrained)
template <int N> __device__ __forceinline__ void waitcnt_vm() {
  if constexpr (N == 0) asm volatile("s_waitcnt vmcnt(0)" ::: "memory");
  else if constexpr (N == 4) asm volatile("s_waitcnt vmcnt(4)" ::: "memory");
  else if constexpr (N == 6) asm volatile("s_waitcnt vmcnt(6)" ::: "memory");
  else if constexpr (N == 8) asm volatile("s_waitcnt vmcnt(8)" ::: "memory");
}

// ---- dtype probe ----
__global__ void probe_kernel(const void* w, int* flag) {
  int tid = threadIdx.x;
  float mx = 0.f;
  for (int i = tid; i < 512; i += 64)
    mx = fmaxf(mx, fabsf(bf2f(((const bf16*)w)[i])));
#pragma unroll
  for (int off = 32; off; off >>= 1) mx = fmaxf(mx, __shfl_xor(mx, off));
  if (tid == 0) *flag = (mx > 1e3f) ? 1 : 0;  // 1 => inputs are fp32
}

__global__ __launch_bounds__(256) void fill_kernel(bf16* out, float v, int n) {
  int idx = blockIdx.x * 256 + threadIdx.x;
  if (idx < n) out[idx] = f2bf(v);
}

// ---- one-time weight conversion: 11 tensors -> bf16 in workspace ----------
struct WLs { const void* s[11]; long d[11]; int n[11]; };
__global__ __launch_bounds__(256) void wconv_kernel(WLs L, bf16* Wb,
                                                    const int* dflag) {
  int f = *dflag;
  int seg = blockIdx.y;
  long n8 = (long)(L.n[seg] >> 3);
  long i = (long)blockIdx.x * 256 + threadIdx.x;
  if (i >= n8) return;
  bf16* d = Wb + L.d[seg] + i * 8;
  if (f) {
    const float4* s = (const float4*)L.s[seg] + i * 2;
    float4 a = s[0], b = s[1];
    union { uint4 u; bf16 h[8]; } pk;
    pk.h[0] = f2bf(a.x); pk.h[1] = f2bf(a.y); pk.h[2] = f2bf(a.z); pk.h[3] = f2bf(a.w);
    pk.h[4] = f2bf(b.x); pk.h[5] = f2bf(b.y); pk.h[6] = f2bf(b.z); pk.h[7] = f2bf(b.w);
    *(uint4*)d = pk.u;
  } else {
    *(uint4*)d = ((const uint4*)L.s[seg])[i];
  }
}

// ---------------- im2col over VISIBLE patches only -> bf16 ----------------
__global__ __launch_bounds__(256) void im2col_vis_kernel(
    const void* __restrict__ x, const int* __restrict__ unmasked,
    bf16* __restrict__ out, const int* __restrict__ dflag) {
  int f = *dflag;
  int idx = blockIdx.x * 256 + threadIdx.x;
  const int TOT = B_ * NVIS_ * 768;
  if (idx >= TOT) return;
  int k = idx % 768;
  int row = idx / 768;
  int j = row % NVIS_;
  int b = row / NVIS_;
  int n = unmasked[b * NVIS_ + j];
  int ph = n / 14, pw = n % 14;
  int c  = k >> 8;
  int rr = (k >> 4) & 15;
  int cc = k & 15;
  out[idx] = f2bf(rdin(x, (long)(((b * 3 + c) * 224) + ph * 16 + rr) * 224 + pw * 16 + cc, f));
}

// ---- MFMA GEMM: gload_lds staging, dbuf BK=64, counted vmcnt, swizzle -----
// Schedule frozen at round-8 config (measured best). Tuning history:
// 128x128/64KB LDS -> -109us (r6, m132); BK=32 -> -65us (r9); counted-vmcnt
// on <=48KB tiles -> neutral (r8). ROUND-11 (re-run; r11 bench was an infra
// failure): wide-N call sites moved cfg1->cfg2 (32KB LDS, 5 blocks/CU) for
// TLP at shallow K (K/64 = 4..6 steps).
// C[M,N] = epi(A[M,K](bf16) @ W[N,K]^T(bf16) + bias)
// MODE 0 plain, 1 exact GELU, 2 += res[f32] (splits must be 1; in-place ok).
// Split-K via grid.z writes DISJOINT f32 partial at C + z*M*N; bias by z==0.
// out_mode: 0 bf16, 1 f32, 2 per dtype flag.
// LDS swizzle: linear DMA dest + XOR-permuted global source chunk + same XOR
// on ds_read chunk (rule #21 both-sides). Requires M%BM==0, N%BN==0, KS%64==0.
#define UNR _Pragma("unroll")
template <int MODE, int TMW, int TNW>
__global__ __launch_bounds__(256) void gemm_kernel(
    const bf16* __restrict__ A, const bf16* __restrict__ W,
    const void* __restrict__ bias, long bOff, const float* __restrict__ res,
    void* __restrict__ C, int M, int N, int K, int KS, int out_mode,
    const int* __restrict__ dflag) {
  constexpr int BM = 2 * TMW, BN = 2 * TNW;
  constexpr int AM = TMW / 16, AN = TNW / 16;
  constexpr int ACH = BM / 32, BCH = BN / 32;  // 32-row staging chunks
  constexpr int VW = ACH + BCH;                // DMAs per STAGE per thread
  int f = *dflag;
  __shared__ bf16 Asl[2][BM * 64];
  __shared__ bf16 Bsl[2][BN * 64];
  int tid = threadIdx.x;

  // XCD-chunked bijective remap (m204)
  int gx = gridDim.x;
  int nwg = gx * gridDim.y;
  int orig = blockIdx.y * gx + blockIdx.x;
  int q = nwg >> 3, rr_ = nwg & 7, xcd = orig & 7, off = orig >> 3;
  int wgid = (xcd < rr_ ? xcd * (q + 1) : rr_ * (q + 1) + (xcd - rr_) * q) + off;
  int bx = wgid % gx, by = wgid / gx, bz = blockIdx.z;

  int w = tid >> 6, lane = tid & 63;
  int quad = lane >> 4, l16 = lane & 15;
  int rb = l16 & 7;  // read-side swizzle key
  int wm = (w & 1) * TMW, wn = (w >> 1) * TNW;
  int srow = tid >> 3;
  int dcol = (tid & 7) * 8;
  int scol = (((tid & 7) ^ (srow & 7))) * 8;
  const bf16* Ab = A + (long)by * BM * K;
  const bf16* Wp = W + (long)bx * BN * K;
  int k0lo = bz * KS;

  float4v acc[AM][AN];
#pragma unroll
  for (int i = 0; i < AM; i++)
#pragma unroll
    for (int j = 0; j < AN; j++) acc[i][j] = (float4v){0.f, 0.f, 0.f, 0.f};

#define STAGE(buf, k0) \
  UNR for (int i_ = 0; i_ < ACH; i_++) { \
    int r_ = i_ * 32 + srow; \
    gll16(Ab + (long)r_ * K + (k0) + scol, &Asl[buf][r_ * 64 + dcol]); } \
  UNR for (int i_ = 0; i_ < BCH; i_++) { \
    int r_ = i_ * 32 + srow; \
    gll16(Wp + (long)r_ * K + (k0) + scol, &Bsl[buf][r_ * 64 + dcol]); }

#define COMPUTE(cur) UNR for (int kk = 0; kk < 2; kk++) { \
    short8 af[AM], bfr[AN]; \
    UNR for (int mi = 0; mi < AM; mi++) \
      af[mi] = *(const short8*)&Asl[cur][(wm + mi * 16 + l16) * 64 + ((kk * 4 + quad) ^ rb) * 8]; \
    UNR for (int ni = 0; ni < AN; ni++) \
      bfr[ni] = *(const short8*)&Bsl[cur][(wn + ni * 16 + l16) * 64 + ((kk * 4 + quad) ^ rb) * 8]; \
    UNR for (int mi = 0; mi < AM; mi++) \
      UNR for (int ni = 0; ni < AN; ni++) \
        acc[mi][ni] = __builtin_amdgcn_mfma_f32_16x16x32_bf16( \
            af[mi], bfr[ni], acc[mi][ni], 0, 0, 0); }

  STAGE(0, k0lo);
  asm volatile("s_waitcnt vmcnt(0)" ::: "memory");
  __builtin_amdgcn_s_barrier();
  int nst = KS >> 6;
  for (int s = 0; s < nst; s++) {
    int cur = s & 1;
    if (s + 1 < nst) {
      STAGE(cur ^ 1, k0lo + (s + 1) * 64);  // stays in flight across barrier
      waitcnt_vm<VW>();                     // only prev stage must be done
    } else {
      asm volatile("s_waitcnt vmcnt(0)" ::: "memory");
    }
    __builtin_amdgcn_s_barrier();  // all waves: cur fully staged
    COMPUTE(cur);
    if (s + 1 < nst) __builtin_amdgcn_s_barrier();  // cur reads done before s+1 STAGE overwrites
  }
#undef STAGE
#undef COMPUTE

  int om = (out_mode == 2) ? (f ? 1 : 0) : out_mode;  // 1=f32, 0=bf16
  float* Cf = (float*)C + (long)bz * M * N;
  bf16*  Cb = (bf16*)C;  // splits never write bf16
#pragma unroll
  for (int mi = 0; mi < AM; mi++) {
#pragma unroll
    for (int ni = 0; ni < AN; ni++) {
      int cn = bx * BN + wn + ni * 16 + l16;
      float bval = (bz == 0) ? rdin(bias, bOff + cn, f) : 0.f;
#pragma unroll
      for (int r = 0; r < 4; r++) {
        int cm = by * BM + wm + mi * 16 + quad * 4 + r;
        float v = acc[mi][ni][r] + bval;
        if constexpr (MODE == 1) v = 0.5f * v * (1.0f + erff(v * 0.70710678f));
        if constexpr (MODE == 2) v += res[(long)cm * N + cn];
        if (om) Cf[(long)cm * N + cn] = v;
        else    Cb[(long)cm * N + cn] = f2bf(v);
      }
    }
  }
}

// ---- LayerNorm fused with residual update: one wave per row (generic) ----
template <int N>
__global__ __launch_bounds__(256) void ln_kernel(
    float* __restrict__ X, const float* __restrict__ G0,
    const float* __restrict__ G1, const float* __restrict__ G2,
    const void* __restrict__ w, long wOff, const void* __restrict__ bv,
    long bOff, bf16* __restrict__ Y, int M, const int* __restrict__ dflag) {
  int f = *dflag;
  int row = blockIdx.x * 4 + (threadIdx.x >> 6);
  int lane = threadIdx.x & 63;
  if (row >= M) return;
  float* xr = X + (long)row * N;
  const float* g0 = G0 ? G0 + (long)row * N : nullptr;
  const float* g1 = G1 ? G1 + (long)row * N : nullptr;
  const float* g2 = G2 ? G2 + (long)row * N : nullptr;
  constexpr int CNT = N / 64;
  float v[CNT];
  float sum = 0.f;
#pragma unroll
  for (int i = 0; i < CNT; i++) {
    int c = lane + 64 * i;
    float t = xr[c];
    if (g0) t += g0[c];
    if (g1) t += g1[c];
    if (g2) t += g2[c];
    if (g0) xr[c] = t;
    v[i] = t;
    sum += t;
  }
#pragma unroll
  for (int off = 32; off; off >>= 1) sum += __shfl_xor(sum, off);
  float mean = sum * (1.0f / N);
  float vs = 0.f;
#pragma unroll
  for (int i = 0; i < CNT; i++) { float d = v[i] - mean; vs += d * d; }
#pragma unroll
  for (int off = 32; off; off >>= 1) vs += __shfl_xor(vs, off);
  float rstd = rsqrtf(vs * (1.0f / N) + 1e-5f);
  bf16* yr = Y + (long)row * N;
#pragma unroll
  for (int i = 0; i < CNT; i++) {
    int cidx = lane + 64 * i;
    yr[cidx] = f2bf((v[i] - mean) * rstd * rdin(w, wOff + cidx, f) + rdin(bv, bOff + cidx, f));
  }
}

// ---- LayerNorm N=256, vectorized (G13): lane owns 4 consecutive cols ------
__global__ __launch_bounds__(256) void ln256_kernel(
    const float* __restrict__ X, const void* __restrict__ w, long wOff,
    const void* __restrict__ bv, long bOff, bf16* __restrict__ Y, int M,
    const int* __restrict__ dflag) {
  int f = *dflag;
  int row = blockIdx.x * 4 + (threadIdx.x >> 6);
  int lane = threadIdx.x & 63;
  if (row >= M) return;
  float4 v = *(const float4*)(X + (long)row * 256 + lane * 4);
  float sum = v.x + v.y + v.z + v.w;
#pragma unroll
  for (int off = 32; off; off >>= 1) sum += __shfl_xor(sum, off);
  float mean = sum * (1.0f / 256.0f);
  float dx = v.x - mean, dy = v.y - mean, dz = v.z - mean, dw = v.w - mean;
  float vs = dx * dx + dy * dy + dz * dz + dw * dw;
#pragma unroll
  for (int off = 32; off; off >>= 1) vs += __shfl_xor(vs, off);
  float rstd = rsqrtf(vs * (1.0f / 256.0f) + 1e-5f);
  float w0, w1, w2, w3, b0, b1, b2, b3;
  if (f) {
    float4 wv = *(const float4*)((const float*)w + wOff + lane * 4);
    float4 bb = *(const float4*)((const float*)bv + bOff + lane * 4);
    w0 = wv.x; w1 = wv.y; w2 = wv.z; w3 = wv.w;
    b0 = bb.x; b1 = bb.y; b2 = bb.z; b3 = bb.w;
  } else {
    const bf16* wp = (const bf16*)w + wOff + lane * 4;
    const bf16* bp = (const bf16*)bv + bOff + lane * 4;
    w0 = bf2f(wp[0]); w1 = bf2f(wp[1]); w2 = bf2f(wp[2]); w3 = bf2f(wp[3]);
    b0 = bf2f(bp[0]); b1 = bf2f(bp[1]); b2 = bf2f(bp[2]); b3 = bf2f(bp[3]);
  }
  union { short4 s4; bf16 h[4]; } o;
  o.h[0] = f2bf(dx * rstd * w0 + b0);
  o.h[1] = f2bf(dy * rstd * w1 + b1);
  o.h[2] = f2bf(dz * rstd * w2 + b2);
  o.h[3] = f2bf(dw * rstd * w3 + b3);
  *(short4*)(Y + (long)row * 256 + lane * 4) = o.s4;
}

// ---- decoder attention, MFMA flash: S=196, DH=32, H=8 --------------------
__global__ __launch_bounds__(256) void attn_dec_kernel(
    const bf16* __restrict__ qkv, bf16* __restrict__ out) {
  const int S = SDEC_, DH = 32, Dm = 256, tri = 768;
  const int KLD = 40, VLD = 232, PLD = 232;
  int b = blockIdx.x >> 3, h = blockIdx.x & 7;
  __shared__ bf16 Ksh[208 * KLD];
  __shared__ bf16 Vt[32 * VLD];
  __shared__ bf16 Psh[4][16 * PLD];
  int tid = threadIdx.x;
  const bf16* base = qkv + (long)b * S * tri;
  for (int idx = tid; idx < S * 4; idx += 256) {
    int s = idx >> 2, part = (idx & 3) * 8;
    uint4 v = *(const uint4*)(base + (long)s * tri + Dm + h * DH + part);
    *(uint4*)(&Ksh[s * KLD + part]) = v;
  }
  if (tid < 12 * 4) {
    int s = 196 + (tid >> 2), part = (tid & 3) * 8;
    uint4 z = {0, 0, 0, 0};
    *(uint4*)(&Ksh[s * KLD + part]) = z;
  }
  for (int idx = tid; idx < S * DH; idx += 256) {
    int s = idx >> 5, d = idx & 31;
    Vt[d * VLD + s] = base[(long)s * tri + 2 * Dm + h * DH + d];
  }
  for (int idx = tid; idx < 32 * 36; idx += 256) {
    int d = idx / 36, c = 196 + idx % 36;
    Vt[d * VLD + c] = f2bf(0.f);
  }
  __syncthreads();
  int w = tid >> 6, lane = tid & 63, l16 = lane & 15, quad = lane >> 4;
  bf16* Pw = &Psh[w][0];
  const float scale = 0.17677669529663687f;
  for (int qt = w; qt < 13; qt += 4) {
    int q0 = qt * 16;
    int qr = min(q0 + l16, S - 1);
    short8 qf = *(const short8*)(base + (long)qr * tri + h * DH + quad * 8);
    float4v sc[13];
#pragma unroll
    for (int t = 0; t < 13; t++) {
      short8 kf = *(const short8*)&Ksh[(t * 16 + l16) * KLD + quad * 8];
      sc[t] = __builtin_amdgcn_mfma_f32_16x16x32_bf16(
          qf, kf, (float4v){0.f, 0.f, 0.f, 0.f}, 0, 0, 0);
    }
    float mx[4] = {-1e30f, -1e30f, -1e30f, -1e30f};
#pragma unroll
    for (int t = 0; t < 13; t++) {
      bool valid = (t * 16 + l16) < S;
#pragma unroll
      for (int r = 0; r < 4; r++) {
        float v = valid ? sc[t][r] * scale : -1e30f;
        sc[t][r] = v;
        mx[r] = fmaxf(mx[r], v);
      }
    }
#pragma unroll
    for (int off = 1; off < 16; off <<= 1)
#pragma unroll
      for (int r = 0; r < 4; r++) mx[r] = fmaxf(mx[r], __shfl_xor(mx[r], off));
    float sm[4] = {0.f, 0.f, 0.f, 0.f};
#pragma unroll
    for (int t = 0; t < 13; t++)
#pragma unroll
      for (int r = 0; r < 4; r++) {
        float p = __expf(sc[t][r] - mx[r]);
        sc[t][r] = p;
        sm[r] += p;
      }
#pragma unroll
    for (int off = 1; off < 16; off <<= 1)
#pragma unroll
      for (int r = 0; r < 4; r++) sm[r] += __shfl_xor(sm[r], off);
#pragma unroll
    for (int t = 0; t < 14; t++) {
      int col = t * 16 + l16;
#pragma unroll
      for (int r = 0; r < 4; r++) {
        float p = (t < 13) ? sc[t][r] : 0.f;
        Pw[(quad * 4 + r) * PLD + col] = f2bf(p);
      }
    }
    __asm__ volatile("s_waitcnt lgkmcnt(0)" ::: "memory");
    float4v o0 = {0.f, 0.f, 0.f, 0.f}, o1 = {0.f, 0.f, 0.f, 0.f};
#pragma unroll
    for (int kc = 0; kc < 7; kc++) {
      short8 pf = *(const short8*)&Pw[l16 * PLD + kc * 32 + quad * 8];
      short8 v0 = *(const short8*)&Vt[l16 * VLD + kc * 32 + quad * 8];
      short8 v1 = *(const short8*)&Vt[(16 + l16) * VLD + kc * 32 + quad * 8];
      o0 = __builtin_amdgcn_mfma_f32_16x16x32_bf16(pf, v0, o0, 0, 0, 0);
      o1 = __builtin_amdgcn_mfma_f32_16x16x32_bf16(pf, v1, o1, 0, 0, 0);
    }
#pragma unroll
    for (int r = 0; r < 4; r++) {
      int row = q0 + quad * 4 + r;
      if (row < S) {
        float inv = 1.f / sm[r];
        bf16* op = out + ((long)(b * S + row)) * Dm + h * DH;
        op[l16]      = f2bf(o0[r] * inv);
        op[16 + l16] = f2bf(o1[r] * inv);
      }
    }
  }
}

// ---- encoder attention: S=50, DH=64, H=6. 128 thr = 2 waves, j-split ------
__global__ __launch_bounds__(128) void attn_enc_kernel(
    const bf16* __restrict__ qkv, bf16* __restrict__ out) {
  const int S = SENC_, H = 6, DH = 64, Dm = H * DH, tri = 3 * Dm;
  int b = blockIdx.x / H, h = blockIdx.x % H;
  int tid = threadIdx.x;
  __shared__ float Ks[SENC_ * 64];
  __shared__ float Vs[SENC_ * 64];
  __shared__ float P1[SENC_ * 66];
  const bf16* base = qkv + (long)b * S * tri;
  for (int idx = tid; idx < S * 8; idx += 128) {
    int s = idx >> 3, part = (idx & 7) * 8;
    union { uint4 u; bf16 hh[8]; } kk, vv;
    kk.u = *(const uint4*)(base + (long)s * tri + Dm + h * DH + part);
    vv.u = *(const uint4*)(base + (long)s * tri + 2 * Dm + h * DH + part);
#pragma unroll
    for (int j = 0; j < 8; j++) {
      Ks[s * DH + part + j] = bf2f(kk.hh[j]);
      Vs[s * DH + part + j] = bf2f(vv.hh[j]);
    }
  }
  __syncthreads();
  int w = tid >> 6, lane = tid & 63;
  int row = lane;
  float q[DH], o[DH];
  float m = -1e30f, l = 0.f;
  if (lane < S) {
    const float scale = 0.125f;
#pragma unroll
    for (int d = 0; d < DH; d++) {
      q[d] = bf2f(base[(long)row * tri + h * DH + d]) * scale;
      o[d] = 0.f;
    }
    int jlo = w * 25, jhi = jlo + 25;
    for (int j = jlo; j < jhi; j++) {
      float s = 0.f;
#pragma unroll
      for (int d = 0; d < DH; d++) s += q[d] * Ks[j * DH + d];
      float mn = fmaxf(m, s);
      float corr = __expf(m - mn);
      float p = __expf(s - mn);
      l = l * corr + p;
      m = mn;
#pragma unroll
      for (int d = 0; d < DH; d++) o[d] = o[d] * corr + p * Vs[j * DH + d];
    }
    if (w == 1) {
#pragma unroll
      for (int d = 0; d < DH; d++) P1[row * 66 + d] = o[d];
      P1[row * 66 + 64] = m;
      P1[row * 66 + 65] = l;
    }
  }
  __syncthreads();
  if (w == 0 && lane < S) {
    float m1 = P1[row * 66 + 64], l1 = P1[row * 66 + 65];
    float mg = fmaxf(m, m1);
    float e0 = __expf(m - mg), e1 = __expf(m1 - mg);
    float lg = l * e0 + l1 * e1;
    float inv = 1.f / lg;
    bf16* op = out + ((long)(b * S + row) * Dm + h * DH);
#pragma unroll
    for (int d = 0; d < DH; d++)
      op[d] = f2bf((o[d] * e0 + P1[row * 66 + d] * e1) * inv);
  }
}

// ---------------- small elementwise kernels ----------------
__global__ __launch_bounds__(256) void build_xe_kernel(
    const float* __restrict__ G0, const float* __restrict__ G1,
    const float* __restrict__ G2, const void* __restrict__ cls,
    const void* __restrict__ pos, const int* __restrict__ unmasked,
    float* __restrict__ xe, const int* __restrict__ dflag) {
  int f = *dflag;
  int idx = blockIdx.x * 256 + threadIdx.x;
  const int TOT = B_ * SENC_ * D_;
  if (idx >= TOT) return;
  int d = idx % D_;
  int s = (idx / D_) % SENC_;
  int b = idx / (D_ * SENC_);
  float v;
  if (s == 0) {
    v = rdin(cls, d, f) + rdin(pos, d, f);
  } else {
    int j = s - 1;
    int n = unmasked[b * NVIS_ + j];
    long r = (long)(b * NVIS_ + j) * D_ + d;
    v = G0[r] + G1[r] + G2[r] + rdin(pos, (long)(1 + n) * D_ + d, f);
  }
  xe[idx] = v;
}

__global__ __launch_bounds__(256) void dec_init_kernel(
    const void* __restrict__ mask_token, const void* __restrict__ dpos,
    float* __restrict__ full, const int* __restrict__ dflag) {
  int f = *dflag;
  int idx = blockIdx.x * 256 + threadIdx.x;
  const int TOT = B_ * NP_ * DD_;
  if (idx >= TOT) return;
  int d = idx % DD_;
  int n = (idx / DD_) % NP_;
  full[idx] = rdin(mask_token, d, f) + rdin(dpos, (long)(1 + n) * DD_ + d, f);
}

__global__ __launch_bounds__(256) void dec_scatter_kernel(
    const float* __restrict__ Gx0, const float* __restrict__ Gx1,
    const int* __restrict__ unmasked, const void* __restrict__ dpos,
    float* __restrict__ full, const int* __restrict__ dflag) {
  int f = *dflag;
  int idx = blockIdx.x * 256 + threadIdx.x;
  const int TOT = B_ * NVIS_ * DD_;
  if (idx >= TOT) return;
  int d = idx % DD_;
  int j = (idx / DD_) % NVIS_;
  int b = idx / (DD_ * NVIS_);
  int n = unmasked[b * NVIS_ + j];
  long r = (long)(b * SENC_ + 1 + j) * DD_ + d;
  full[((long)(b * NP_ + n)) * DD_ + d] =
      Gx0[r] + Gx1[r] + rdin(dpos, (long)(1 + n) * DD_ + d, f);
}

// ---------------- host ----------------
extern "C" void kernel_launch(void* const* d_in, const int* in_sizes, int n_in,
                              void* d_out, int out_size, void* d_ws, size_t ws_size,
                              hipStream_t stream) {
  (void)in_sizes; (void)n_in;
  const int* unmasked = (const int*)d_in[1];
  const int M_ENC = B_ * SENC_;  // 3200
  const int M_DEC = B_ * NP_;    // 12544

  const size_t NEEDED = 87588880;
  if (ws_size < NEEDED) {
    fill_kernel<<<(out_size + 255) / 256, 256, 0, stream>>>(
        (bf16*)d_out, (float)(ws_size >> 20), out_size);
    return;
  }
  char* wsb = (char*)d_ws;
  bf16*  big    = (bf16*)wsb;
  float* full   = (float*)(wsb + 25690112);
  bf16*  im2col = (bf16*)(wsb + 25690112);
  bf16*  t0     = (bf16*)(wsb + 38535168);
  float* xe     = (float*)(wsb + 44957696);
  int*   dflag  = (int*)(wsb + 58884096);
  bf16*  Wb     = (bf16*)(wsb + 58884112);  // 16B-aligned bf16 weights
  float* Gp0 = (float*)(wsb + 0);
  float* Gp1 = (float*)(wsb + 4915200);
  float* Gp2 = (float*)(wsb + 9830400);
  float* Gf0 = (float*)(wsb + 9830400);
  float* Gf1 = (float*)(wsb + 14745600);
  float* Gf2 = (float*)(wsb + 19660800);
  float* Gx0 = (float*)(wsb + 0);
  float* Gx1 = (float*)(wsb + 3276800);

  // bf16 weight offsets (elements)
  const long o_conv = 0,        o_eqkv = 294912,  o_eout = 2949120;
  const long o_efc1 = 3833856,  o_efc2 = 7372800, o_demb = 10911744;
  const long o_dqkv = 11010048, o_dout = 11796480, o_dfc1 = 12058624;
  const long o_dfc2 = 13107200, o_pred = 14155776;

  probe_kernel<<<1, 64, 0, stream>>>(d_in[3], dflag);
  {
    WLs L;
    L.s[0] = d_in[3];  L.d[0] = o_conv; L.n[0] = 294912;
    L.s[1] = d_in[9];  L.d[1] = o_eqkv; L.n[1] = 2654208;
    L.s[2] = d_in[11]; L.d[2] = o_eout; L.n[2] = 884736;
    L.s[3] = d_in[15]; L.d[3] = o_efc1; L.n[3] = 3538944;
    L.s[4] = d_in[17]; L.d[4] = o_efc2; L.n[4] = 3538944;
    L.s[5] = d_in[21]; L.d[5] = o_demb; L.n[5] = 98304;
    L.s[6] = d_in[27]; L.d[6] = o_dqkv; L.n[6] = 786432;
    L.s[7] = d_in[29]; L.d[7] = o_dout; L.n[7] = 262144;
    L.s[8] = d_in[33]; L.d[8] = o_dfc1; L.n[8] = 1048576;
    L.s[9] = d_in[35]; L.d[9] = o_dfc2; L.n[9] = 1048576;
    L.s[10] = d_in[39]; L.d[10] = o_pred; L.n[10] = 196608;
    dim3 g((3538944 / 8 + 255) / 256, 11);
    wconv_kernel<<<g, 256, 0, stream>>>(L, Wb, dflag);
  }

  // cfg: 1 -> 128x64 tile (48KB LDS), 2 -> 64x64 (32KB LDS, 5 blocks/CU).
  auto gemm = [&](int mode, int cfg, const bf16* A, const bf16* Wp,
                  const void* bias, long bOff, const float* res, void* C,
                  int M, int N, int K, int splits, int out_mode) {
    int BM = (cfg == 2) ? 64 : 128;
    dim3 g(N / 64, M / BM, splits);
    int KS = K / splits;
#define GL(MO, TM, TN) gemm_kernel<MO, TM, TN><<<g, 256, 0, stream>>>( \
        A, Wp, bias, bOff, res, C, M, N, K, KS, out_mode, dflag)
    if (mode == 0) {
      if (cfg == 1) GL(0, 64, 32); else GL(0, 32, 32);
    } else if (mode == 1) {
      if (cfg == 1) GL(1, 64, 32); else GL(1, 32, 32);
    } else {
      if (cfg == 1) GL(2, 64, 32); else GL(2, 32, 32);
    }
#undef GL
  };

  // ---- patchify (visible patches only), split-K x3 -> disjoint partials ----
  {
    int tot = B_ * NVIS_ * 768;
    im2col_vis_kernel<<<(tot + 255) / 256, 256, 0, stream>>>(d_in[0], unmasked, im2col, dflag);
    gemm(0, 2, im2col, Wb + o_conv, d_in[4], 0, nullptr, Gp0, 3200, D_, 768, 3, 1);
    int tot2 = B_ * SENC_ * D_;
    build_xe_kernel<<<(tot2 + 255) / 256, 256, 0, stream>>>(
        Gp0, Gp1, Gp2, d_in[5], d_in[6], unmasked, xe, dflag);
  }

  // ---- encoder: 6 blocks, S=50, D=384, H=6, dh=64 ----
  const float *eg0 = nullptr, *eg1 = nullptr, *eg2 = nullptr;
  for (int i = 0; i < 6; i++) {
    ln_kernel<D_><<<M_ENC / 4, 256, 0, stream>>>(
        xe, eg0, eg1, eg2, d_in[7], (long)i * D_, d_in[8], (long)i * D_, t0, M_ENC, dflag);
    gemm(0, 2, t0, Wb + o_eqkv + (long)i * 3 * D_ * D_, d_in[10], (long)i * 3 * D_, nullptr, big, M_ENC, 3 * D_, D_, 1, 0);
    attn_enc_kernel<<<B_ * 6, 128, 0, stream>>>(big, t0);
    gemm(0, 2, t0, Wb + o_eout + (long)i * D_ * D_, d_in[12], (long)i * D_, nullptr, Gp0, M_ENC, D_, D_, 2, 1);
    ln_kernel<D_><<<M_ENC / 4, 256, 0, stream>>>(
        xe, Gp0, Gp1, nullptr, d_in[13], (long)i * D_, d_in[14], (long)i * D_, t0, M_ENC, dflag);
    gemm(1, 2, t0, Wb + o_efc1 + (long)i * 4 * D_ * D_, d_in[16], (long)i * 4 * D_, nullptr, big, M_ENC, 4 * D_, D_, 1, 0);
    gemm(0, 2, big, Wb + o_efc2 + (long)i * D_ * 4 * D_, d_in[18], (long)i * D_, nullptr, Gf0, M_ENC, D_, 4 * D_, 3, 1);
    eg0 = Gf0; eg1 = Gf1; eg2 = Gf2;
  }
  ln_kernel<D_><<<M_ENC / 4, 256, 0, stream>>>(
      xe, Gf0, Gf1, Gf2, d_in[19], 0, d_in[20], 0, t0, M_ENC, dflag);
  gemm(0, 2, t0, Wb + o_demb, d_in[22], 0, nullptr, Gx0, M_ENC, DD_, D_, 2, 1);

  // ---- assemble decoder input ----
  {
    int tot = B_ * NP_ * DD_;
    dec_init_kernel<<<(tot + 255) / 256, 256, 0, stream>>>(d_in[23], d_in[24], full, dflag);
    int tot2 = B_ * NVIS_ * DD_;
    dec_scatter_kernel<<<(tot2 + 255) / 256, 256, 0, stream>>>(
        Gx0, Gx1, unmasked, d_in[24], full, dflag);
  }

  // ---- decoder: 4 blocks, S=196, D=256, H=8, dh=32 ----
  // residual fused into GEMM epilogue (MODE 2, splits=1): full updated in place
  for (int i = 0; i < 4; i++) {
    ln256_kernel<<<M_DEC / 4, 256, 0, stream>>>(
        full, d_in[25], (long)i * DD_, d_in[26], (long)i * DD_, t0, M_DEC, dflag);
    gemm(0, 2, t0, Wb + o_dqkv + (long)i * 3 * DD_ * DD_, d_in[28], (long)i * 3 * DD_, nullptr, big, M_DEC, 3 * DD_, DD_, 1, 0);
    attn_dec_kernel<<<B_ * 8, 256, 0, stream>>>(big, t0);
    gemm(2, 2, t0, Wb + o_dout + (long)i * DD_ * DD_, d_in[30], (long)i * DD_, full, full, M_DEC, DD_, DD_, 1, 1);
    ln256_kernel<<<M_DEC / 4, 256, 0, stream>>>(
        full, d_in[31], (long)i * DD_, d_in[32], (long)i * DD_, t0, M_DEC, dflag);
    gemm(1, 2, t0, Wb + o_dfc1 + (long)i * 4 * DD_ * DD_, d_in[34], (long)i * 4 * DD_, nullptr, big, M_DEC, 4 * DD_, DD_, 1, 0);
    gemm(2, 2, big, Wb + o_dfc2 + (long)i * DD_ * 4 * DD_, d_in[36], (long)i * DD_, full, full, M_DEC, DD_, 4 * DD_, 1, 1);
  }
  ln256_kernel<<<M_DEC / 4, 256, 0, stream>>>(
      full, d_in[37], 0, d_in[38], 0, t0, M_DEC, dflag);

  // ---- predictor head: output dtype follows input dtype ----
  gemm(0, 2, t0, Wb + o_pred, d_in[40], 0, nullptr, d_out, M_DEC, 768, DD_, 1, 2);
}